// Round 1
// baseline (12000.319 us; speedup 1.0000x reference)
//
#include <hip/hip_runtime.h>
#include <math.h>

#define L_ 6
#define H_ 6
#define HS_ 64
#define D_ 384
#define T_ 256
#define V_ 65
#define B_ 64
#define ROWS (B_*T_)        // 16384
#define EPS_ 1e-5f

// ---------------------------------------------------------------- embedding
__global__ void embed_kernel(const int* __restrict__ idx,
                             const float* __restrict__ tok,
                             const float* __restrict__ pos,
                             float* __restrict__ x) {
    int i = blockIdx.x * blockDim.x + threadIdx.x;   // < ROWS*D_
    int d = i % D_;
    int row = i / D_;
    int t = row % T_;
    x[i] = tok[idx[row]*D_ + d] + pos[t*D_ + d];
}

// ---------------------------------------------------------------- layernorm
// one block (128 threads) per row, D=384 -> 3 elems/thread
__global__ __launch_bounds__(128)
void ln_kernel(const float* __restrict__ x,
               const float* __restrict__ g,
               const float* __restrict__ b,
               float* __restrict__ y) {
    int row = blockIdx.x;
    int tid = threadIdx.x;
    const float* xr = x + (size_t)row * D_;
    float v0 = xr[tid], v1 = xr[tid+128], v2 = xr[tid+256];
    float s  = v0+v1+v2;
    float sq = v0*v0+v1*v1+v2*v2;
    for (int off = 32; off; off >>= 1) {
        s  += __shfl_xor(s,  off);
        sq += __shfl_xor(sq, off);
    }
    __shared__ float red[4];
    int wid = tid >> 6, lane = tid & 63;
    if (lane == 0) { red[wid*2] = s; red[wid*2+1] = sq; }
    __syncthreads();
    float sum   = red[0] + red[2];
    float sumsq = red[1] + red[3];
    float mean = sum * (1.0f/D_);
    float var  = sumsq * (1.0f/D_) - mean*mean;
    float rstd = rsqrtf(var + EPS_);
    float* yr = y + (size_t)row * D_;
    yr[tid]     = (v0 - mean)*rstd*g[tid]     + b[tid];
    yr[tid+128] = (v1 - mean)*rstd*g[tid+128] + b[tid+128];
    yr[tid+256] = (v2 - mean)*rstd*g[tid+256] + b[tid+256];
}

// ---------------------------------------------------------------- SGEMM
// C[M,N] = res + act(A[M,K] @ B + bias)
// B element (k, n) at  B[(n/hb)*hstride + k*kstride + (n%hb)]
//   row-major [K,N]: hb=N, hstride=0, kstride=N
//   per-head  [H,K,HS]: hb=HS, hstride=K*HS, kstride=HS
// 64x64 tile, BK=16, 256 threads, 4x4 per thread.
__global__ __launch_bounds__(256)
void sgemm(const float* __restrict__ A, const float* __restrict__ Bm,
           const float* __restrict__ bias, const float* __restrict__ res,
           float* __restrict__ C, int M, int N, int K,
           int hb, int hstride, int kstride, int relu)
{
    __shared__ float As[16][64];
    __shared__ float Bs[16][64];
    int tid = threadIdx.x;
    int tx = tid & 15, ty = tid >> 4;
    int m0 = blockIdx.y * 64;
    int n0 = blockIdx.x * 64;

    // B-load mapping for this thread (4 consecutive columns)
    int bk  = tid >> 4;              // tile row (k) 0..15
    int bn0 = (tid & 15) * 4;        // tile col base
    int hblk[4], nn[4], nv[4];
    #pragma unroll
    for (int j = 0; j < 4; ++j) {
        int n = n0 + bn0 + j;
        nv[j]   = (n < N);
        hblk[j] = nv[j] ? (n / hb) : 0;
        nn[j]   = nv[j] ? (n % hb) : 0;
    }
    // A-load mapping
    int amr = tid >> 2;              // 0..63
    int aks = (tid & 3) * 4;         // 0,4,8,12

    float acc[4][4] = {};
    for (int k0 = 0; k0 < K; k0 += 16) {
        const float4 a4 = *reinterpret_cast<const float4*>(
            A + (size_t)(m0+amr)*K + k0 + aks);
        As[aks+0][amr] = a4.x; As[aks+1][amr] = a4.y;
        As[aks+2][amr] = a4.z; As[aks+3][amr] = a4.w;
        #pragma unroll
        for (int j = 0; j < 4; ++j) {
            float vbl = 0.f;
            if (nv[j])
                vbl = Bm[(size_t)hblk[j]*hstride + (size_t)(k0+bk)*kstride + nn[j]];
            Bs[bk][bn0 + j] = vbl;
        }
        __syncthreads();
        #pragma unroll
        for (int kk = 0; kk < 16; ++kk) {
            float ar[4], br[4];
            #pragma unroll
            for (int i = 0; i < 4; ++i) ar[i] = As[kk][ty*4+i];
            #pragma unroll
            for (int j = 0; j < 4; ++j) br[j] = Bs[kk][tx*4+j];
            #pragma unroll
            for (int i = 0; i < 4; ++i)
                #pragma unroll
                for (int j = 0; j < 4; ++j)
                    acc[i][j] += ar[i]*br[j];
        }
        __syncthreads();
    }
    #pragma unroll
    for (int i = 0; i < 4; ++i) {
        int m = m0 + ty*4 + i;
        #pragma unroll
        for (int j = 0; j < 4; ++j) {
            int n = n0 + tx*4 + j;
            if (n < N) {
                float vv = acc[i][j];
                if (bias) vv += bias[n];
                if (relu) vv = fmaxf(vv, 0.f);
                if (res)  vv += res[(size_t)m*N + n];
                C[(size_t)m*N + n] = vv;
            }
        }
    }
}

// ---------------------------------------------------------------- attention
// one block per (b,h,t); q/k/v layout [B,T,H*HS]
__global__ __launch_bounds__(256)
void attn_kernel(const float* __restrict__ q, const float* __restrict__ k,
                 const float* __restrict__ v, float* __restrict__ o)
{
    __shared__ float qs[64];
    __shared__ float pr[256];
    __shared__ float red[4];
    __shared__ float op[4][64];
    int bid = blockIdx.x;
    int t = bid % T_;
    int h = (bid / T_) % H_;
    int b = bid / (T_*H_);
    int tid = threadIdx.x;
    const float scale = 0.05103103630798288f;   // 1/sqrt(384)
    size_t base = ((size_t)b*T_)*D_ + (size_t)h*HS_;

    if (tid < 64) qs[tid] = q[base + (size_t)t*D_ + tid] * scale;
    __syncthreads();

    int s = tid;
    float sc = -INFINITY;
    if (s <= t) {
        const float4* kr = reinterpret_cast<const float4*>(k + base + (size_t)s*D_);
        const float4* q4 = reinterpret_cast<const float4*>(qs);
        float d = 0.f;
        #pragma unroll
        for (int e = 0; e < 16; ++e) {
            float4 kk4 = kr[e]; float4 qq4 = q4[e];
            d += qq4.x*kk4.x + qq4.y*kk4.y + qq4.z*kk4.z + qq4.w*kk4.w;
        }
        sc = d;
    }
    // block max
    float m = sc;
    for (int off = 32; off; off >>= 1) m = fmaxf(m, __shfl_xor(m, off));
    int lane = tid & 63, wid = tid >> 6;
    if (lane == 0) red[wid] = m;
    __syncthreads();
    m = fmaxf(fmaxf(red[0], red[1]), fmaxf(red[2], red[3]));
    float p = (s <= t) ? expf(sc - m) : 0.f;
    pr[tid] = p;
    float sum = p;
    for (int off = 32; off; off >>= 1) sum += __shfl_xor(sum, off);
    __syncthreads();                 // red reuse barrier
    if (lane == 0) red[wid] = sum;
    __syncthreads();
    sum = red[0]+red[1]+red[2]+red[3];
    float inv = 1.0f / sum;

    int gq = tid >> 6;               // 0..3  (s-chunk)
    int e  = tid & 63;
    float part = 0.f;
    int s_end = min(t, gq*64 + 63);
    for (int ss = gq*64; ss <= s_end; ++ss)
        part += pr[ss] * v[base + (size_t)ss*D_ + e];
    op[gq][e] = part;
    __syncthreads();
    if (tid < 64)
        o[base + (size_t)t*D_ + tid] =
            (op[0][tid]+op[1][tid]+op[2][tid]+op[3][tid]) * inv;
}

// ---------------------------------------------------------------- loss
// one wave per row of logits [ROWS, V]
__global__ __launch_bounds__(256)
void loss_kernel(const float* __restrict__ logits,
                 const int* __restrict__ tg,
                 float* __restrict__ loss)
{
    int gid = blockIdx.x * blockDim.x + threadIdx.x;
    int row = gid >> 6;
    int lane = gid & 63;
    const float* lr = logits + (size_t)row * V_;
    float m = -INFINITY;
    for (int c = lane; c < V_; c += 64) m = fmaxf(m, lr[c]);
    for (int off = 32; off; off >>= 1) m = fmaxf(m, __shfl_xor(m, off));
    float s = 0.f;
    for (int c = lane; c < V_; c += 64) s += expf(lr[c] - m);
    for (int off = 32; off; off >>= 1) s += __shfl_xor(s, off);
    if (lane == 0) {
        float lp = lr[tg[row]] - m - logf(s);
        atomicAdd(loss, -lp * (1.0f/ROWS));
    }
}

// ---------------------------------------------------------------- launch
extern "C" void kernel_launch(void* const* d_in, const int* in_sizes, int n_in,
                              void* d_out, int out_size, void* d_ws, size_t ws_size,
                              hipStream_t stream)
{
    const int*   idx     = (const int*)  d_in[0];
    const int*   targets = (const int*)  d_in[1];
    const float* tok     = (const float*)d_in[2];
    const float* pos     = (const float*)d_in[3];
    const float* Wq      = (const float*)d_in[4];
    const float* Wk      = (const float*)d_in[5];
    const float* Wv      = (const float*)d_in[6];
    const float* Wproj   = (const float*)d_in[7];
    const float* bproj   = (const float*)d_in[8];
    const float* W1      = (const float*)d_in[9];
    const float* b1      = (const float*)d_in[10];
    const float* W2      = (const float*)d_in[11];
    const float* b2      = (const float*)d_in[12];
    const float* ln1g    = (const float*)d_in[13];
    const float* ln1b    = (const float*)d_in[14];
    const float* lnfg    = (const float*)d_in[15];
    const float* lnfb    = (const float*)d_in[16];
    const float* Whead   = (const float*)d_in[17];
    const float* bhead   = (const float*)d_in[18];

    float* logits = (float*)d_out;
    float* loss   = logits + (size_t)ROWS * V_;

    const size_t S = (size_t)ROWS * D_;   // 6291456 floats
    float* x   = (float*)d_ws;
    float* y   = x + S;
    float* q   = x + 2*S;
    float* kk  = x + 3*S;
    float* v   = x + 4*S;
    float* o   = x + 5*S;
    float* hid = x + 2*S;                 // reuses q..o (4S floats) after attn

    embed_kernel<<<(ROWS*D_)/256, 256, 0, stream>>>(idx, tok, pos, x);

    dim3 gq(D_/64, ROWS/64);              // (6,256)
    dim3 g1(4*D_/64, ROWS/64);            // (24,256)
    dim3 gh((V_+63)/64, ROWS/64);         // (2,256)

    for (int l = 0; l < L_; ++l) {
        ln_kernel<<<ROWS, 128, 0, stream>>>(x, ln1g + l*D_, ln1b + l*D_, y);
        const size_t wOff = (size_t)l * H_ * D_ * HS_;
        sgemm<<<gq, 256, 0, stream>>>(y, Wq + wOff, nullptr, nullptr, q,
                                      ROWS, D_, D_, HS_, D_*HS_, HS_, 0);
        sgemm<<<gq, 256, 0, stream>>>(y, Wk + wOff, nullptr, nullptr, kk,
                                      ROWS, D_, D_, HS_, D_*HS_, HS_, 0);
        sgemm<<<gq, 256, 0, stream>>>(y, Wv + wOff, nullptr, nullptr, v,
                                      ROWS, D_, D_, HS_, D_*HS_, HS_, 0);
        attn_kernel<<<B_*H_*T_, 256, 0, stream>>>(q, kk, v, o);
        sgemm<<<gq, 256, 0, stream>>>(o, Wproj + (size_t)l*D_*D_, bproj + l*D_, x, x,
                                      ROWS, D_, D_, D_, 0, D_, 0);
        ln_kernel<<<ROWS, 128, 0, stream>>>(x, ln1g + l*D_, ln1b + l*D_, y);
        sgemm<<<g1, 256, 0, stream>>>(y, W1 + (size_t)l*D_*4*D_, b1 + l*4*D_, nullptr, hid,
                                      ROWS, 4*D_, D_, 4*D_, 0, 4*D_, 1);
        sgemm<<<gq, 256, 0, stream>>>(hid, W2 + (size_t)l*4*D_*D_, b2 + l*D_, x, x,
                                      ROWS, D_, 4*D_, D_, 0, D_, 0);
    }
    ln_kernel<<<ROWS, 128, 0, stream>>>(x, lnfg, lnfb, y);
    sgemm<<<gh, 256, 0, stream>>>(y, Whead, bhead, nullptr, logits,
                                  ROWS, V_, D_, V_, 0, V_, 0);
    hipMemsetAsync(loss, 0, sizeof(float), stream);
    loss_kernel<<<ROWS/4, 256, 0, stream>>>(logits, targets, loss);
}

// Round 2
// 3021.244 us; speedup vs baseline: 3.9720x; 3.9720x over previous
//
#include <hip/hip_runtime.h>
#include <math.h>

#define L_ 6
#define H_ 6
#define HS_ 64
#define D_ 384
#define T_ 256
#define V_ 65
#define B_ 64
#define ROWS (B_*T_)        // 16384
#define QKVN 1152
#define EPS_ 1e-5f

typedef __attribute__((ext_vector_type(8))) __bf16 bf16x8;
typedef __attribute__((ext_vector_type(4))) float f32x4;

__device__ __forceinline__ bf16x8 u4_to_bf8(uint4 u) {
    return __builtin_bit_cast(bf16x8, u);
}

// ---------------------------------------------------------------- embedding
__global__ void embed_kernel(const int* __restrict__ idx,
                             const float* __restrict__ tok,
                             const float* __restrict__ pos,
                             float* __restrict__ x) {
    int i = blockIdx.x * blockDim.x + threadIdx.x;   // < ROWS*D_
    int d = i % D_;
    int row = i / D_;
    int t = row % T_;
    x[i] = tok[idx[row]*D_ + d] + pos[t*D_ + d];
}

// ---------------------------------------------------------------- layernorm
// one block (128 threads) per row, D=384 -> 3 elems/thread.
// writes fp32 (optional) and bf16 (optional) outputs.
__global__ __launch_bounds__(128)
void ln_kernel(const float* __restrict__ x,
               const float* __restrict__ g,
               const float* __restrict__ b,
               float* __restrict__ yf,
               __bf16* __restrict__ yb) {
    int row = blockIdx.x;
    int tid = threadIdx.x;
    const float* xr = x + (size_t)row * D_;
    float v0 = xr[tid], v1 = xr[tid+128], v2 = xr[tid+256];
    float s  = v0+v1+v2;
    float sq = v0*v0+v1*v1+v2*v2;
    for (int off = 32; off; off >>= 1) {
        s  += __shfl_xor(s,  off);
        sq += __shfl_xor(sq, off);
    }
    __shared__ float red[4];
    int wid = tid >> 6, lane = tid & 63;
    if (lane == 0) { red[wid*2] = s; red[wid*2+1] = sq; }
    __syncthreads();
    float sum   = red[0] + red[2];
    float sumsq = red[1] + red[3];
    float mean = sum * (1.0f/D_);
    float var  = sumsq * (1.0f/D_) - mean*mean;
    float rstd = rsqrtf(var + EPS_);
    float o0 = (v0 - mean)*rstd*g[tid]     + b[tid];
    float o1 = (v1 - mean)*rstd*g[tid+128] + b[tid+128];
    float o2 = (v2 - mean)*rstd*g[tid+256] + b[tid+256];
    if (yf) {
        float* yr = yf + (size_t)row * D_;
        yr[tid] = o0; yr[tid+128] = o1; yr[tid+256] = o2;
    }
    if (yb) {
        __bf16* yr = yb + (size_t)row * D_;
        yr[tid] = (__bf16)o0; yr[tid+128] = (__bf16)o1; yr[tid+256] = (__bf16)o2;
    }
}

// ---------------------------------------------------------------- transpose+cast
// src fp32 [R][C] row-major (slab z at src + z*R*C)
// dst bf16 [C][R]  at dst + dbase + (z/zdiv)*sA + (z%zdiv)*sB
__global__ __launch_bounds__(256)
void transpose_cast(const float* __restrict__ src, __bf16* __restrict__ dst,
                    int R, int C, int zdiv, long sA, long sB, long dbase)
{
    __shared__ float tile[32][33];
    int z = blockIdx.z;
    const float* s = src + (long)z * R * C;
    __bf16* d = dst + dbase + (long)(z / zdiv) * sA + (long)(z % zdiv) * sB;
    int c0 = blockIdx.x * 32, r0 = blockIdx.y * 32;
    int t = threadIdx.x;
    int tr = t >> 3, tc = (t & 7) * 4;
    float4 v = *(const float4*)(s + (long)(r0 + tr) * C + c0 + tc);
    tile[tr][tc+0] = v.x; tile[tr][tc+1] = v.y;
    tile[tr][tc+2] = v.z; tile[tr][tc+3] = v.w;
    __syncthreads();
    #pragma unroll
    for (int j = 0; j < 4; ++j)
        d[(long)(c0 + tr) * R + r0 + tc + j] = (__bf16)tile[tc+j][tr];
}

// ---------------------------------------------------------------- bf16 MFMA GEMM
// C[M,N] = act(A[M,K] @ Bt^T + bias) (+res);  Bt is [N][K] bf16 (pre-transposed)
// 128x128 tile, BK=32, 256 thr = 4 waves, each wave 64x64 via 4x4 mfma tiles.
__global__ __launch_bounds__(256)
void gemm_bf16(const __bf16* __restrict__ A, const __bf16* __restrict__ Bt,
               const float* __restrict__ bias, const float* res,
               float* outF, __bf16* outB,
               int K, int N, int relu)
{
    __shared__ uint4 As[128*7];    // row stride 7 uint4 (56 bf16: 32 data + pad)
    __shared__ uint4 Bs[128*7];
    int t = threadIdx.x;
    int n0 = blockIdx.x * 128, m0 = blockIdx.y * 128;
    int lane = t & 63, wave = t >> 6;
    int wm = (wave >> 1) * 64, wn = (wave & 1) * 64;
    int ln = lane & 15, quad = lane >> 4;

    f32x4 acc[4][4] = {};

    int c0r = t >> 2, c0s = t & 3;       // chunk t      (rows 0..63)
    int c1r = c0r + 64;                  // chunk t+256  (rows 64..127)
    const __bf16* Ab = A  + (size_t)m0 * K;
    const __bf16* Bb = Bt + (size_t)n0 * K;

    for (int k0 = 0; k0 < K; k0 += 32) {
        As[c0r*7 + c0s] = *(const uint4*)(Ab + (size_t)c0r*K + k0 + c0s*8);
        As[c1r*7 + c0s] = *(const uint4*)(Ab + (size_t)c1r*K + k0 + c0s*8);
        Bs[c0r*7 + c0s] = *(const uint4*)(Bb + (size_t)c0r*K + k0 + c0s*8);
        Bs[c1r*7 + c0s] = *(const uint4*)(Bb + (size_t)c1r*K + k0 + c0s*8);
        __syncthreads();
        bf16x8 af[4], bfr[4];
        #pragma unroll
        for (int i = 0; i < 4; ++i)
            af[i] = __builtin_bit_cast(bf16x8, As[(wm + i*16 + ln)*7 + quad]);
        #pragma unroll
        for (int j = 0; j < 4; ++j)
            bfr[j] = __builtin_bit_cast(bf16x8, Bs[(wn + j*16 + ln)*7 + quad]);
        #pragma unroll
        for (int i = 0; i < 4; ++i)
            #pragma unroll
            for (int j = 0; j < 4; ++j)
                acc[i][j] = __builtin_amdgcn_mfma_f32_16x16x32_bf16(
                                af[i], bfr[j], acc[i][j], 0, 0, 0);
        __syncthreads();
    }
    #pragma unroll
    for (int i = 0; i < 4; ++i) {
        #pragma unroll
        for (int r = 0; r < 4; ++r) {
            int row = m0 + wm + i*16 + quad*4 + r;
            #pragma unroll
            for (int j = 0; j < 4; ++j) {
                int col = n0 + wn + j*16 + ln;
                float v = acc[i][j][r];
                if (bias) v += bias[col];
                if (relu) v = fmaxf(v, 0.f);
                if (res)  v += res[(size_t)row*N + col];
                if (outF) outF[(size_t)row*N + col] = v;
                if (outB) outB[(size_t)row*N + col] = (__bf16)v;
            }
        }
    }
}

// ---------------------------------------------------------------- attention
// block per (b, h, 32-query tile). qkv bf16 [ROWS][1152] (q|k|v cols).
// K/V s-tiles of 64 staged in LDS, online softmax, 8 out accs/thread.
__global__ __launch_bounds__(256)
void attn2(const __bf16* __restrict__ qkv, __bf16* __restrict__ o)
{
    __shared__ float Qs[32][72];
    __shared__ float Ks[64][68];
    __shared__ float Vs[64][68];
    __shared__ float Ss[32][65];
    __shared__ float mrow[32], lrow[32], arow[32];
    int bid = blockIdx.x;
    int qt = bid & 7;
    int h  = (bid >> 3) % H_;
    int b  = bid / (8 * H_);
    int t  = threadIdx.x;
    const float scale = 0.05103103630798288f;   // 1/sqrt(384)
    const size_t rb = (size_t)b * T_ * QKVN + (size_t)h * HS_;

    // stage Q (scaled): 32 rows x 64 e, one 8-elem chunk per thread
    {
        int r = t >> 3, e0 = (t & 7) * 8;
        uint4 uq = *(const uint4*)(qkv + rb + (size_t)(qt*32 + r)*QKVN + e0);
        bf16x8 q8 = u4_to_bf8(uq);
        float4 a = { (float)q8[0]*scale, (float)q8[1]*scale,
                     (float)q8[2]*scale, (float)q8[3]*scale };
        float4 c = { (float)q8[4]*scale, (float)q8[5]*scale,
                     (float)q8[6]*scale, (float)q8[7]*scale };
        *(float4*)&Qs[r][e0]   = a;
        *(float4*)&Qs[r][e0+4] = c;
    }
    if (t < 32) { mrow[t] = -INFINITY; lrow[t] = 0.f; }

    float av[8] = {};
    int ar = t >> 3, ae = (t & 7) * 8;
    int tx = t & 15, ty = t >> 4;
    int st_max = qt >> 1;

    for (int st = 0; st <= st_max; ++st) {
        __syncthreads();   // Q/prev-tile consumers done before restage
        for (int c = t; c < 512; c += 256) {
            int r = c >> 3, e0 = (c & 7) * 8;
            uint4 uk = *(const uint4*)(qkv + rb + 384 + (size_t)(st*64 + r)*QKVN + e0);
            uint4 uv = *(const uint4*)(qkv + rb + 768 + (size_t)(st*64 + r)*QKVN + e0);
            bf16x8 k8 = u4_to_bf8(uk);
            bf16x8 v8 = u4_to_bf8(uv);
            float4 ka = {(float)k8[0],(float)k8[1],(float)k8[2],(float)k8[3]};
            float4 kb = {(float)k8[4],(float)k8[5],(float)k8[6],(float)k8[7]};
            float4 va = {(float)v8[0],(float)v8[1],(float)v8[2],(float)v8[3]};
            float4 vb = {(float)v8[4],(float)v8[5],(float)v8[6],(float)v8[7]};
            *(float4*)&Ks[r][e0]   = ka;  *(float4*)&Ks[r][e0+4] = kb;
            *(float4*)&Vs[r][e0]   = va;  *(float4*)&Vs[r][e0+4] = vb;
        }
        __syncthreads();
        // scores: thread -> rows {ty*2, ty*2+1}, cols {tx, tx+16, tx+32, tx+48}
        float sc[2][4] = {};
        for (int e4 = 0; e4 < 16; ++e4) {
            float4 qa0 = *(const float4*)&Qs[ty*2+0][e4*4];
            float4 qa1 = *(const float4*)&Qs[ty*2+1][e4*4];
            #pragma unroll
            for (int j = 0; j < 4; ++j) {
                float4 kb = *(const float4*)&Ks[tx + 16*j][e4*4];
                sc[0][j] += qa0.x*kb.x + qa0.y*kb.y + qa0.z*kb.z + qa0.w*kb.w;
                sc[1][j] += qa1.x*kb.x + qa1.y*kb.y + qa1.z*kb.z + qa1.w*kb.w;
            }
        }
        int diag = (st == st_max);
        #pragma unroll
        for (int i = 0; i < 2; ++i) {
            int r = ty*2 + i;
            #pragma unroll
            for (int j = 0; j < 4; ++j) {
                int s = tx + 16*j;
                float vsc = sc[i][j];
                if (diag && (st*64 + s) > (qt*32 + r)) vsc = -INFINITY;
                Ss[r][s] = vsc;
            }
        }
        __syncthreads();
        if (t < 32) {
            float m0 = mrow[t], nm = m0;
            #pragma unroll 8
            for (int s = 0; s < 64; ++s) nm = fmaxf(nm, Ss[t][s]);
            float alpha = __expf(m0 - nm);      // m0=-inf first tile -> 0
            float sum = 0.f;
            #pragma unroll 8
            for (int s = 0; s < 64; ++s) {
                float p = __expf(Ss[t][s] - nm);
                Ss[t][s] = p;
                sum += p;
            }
            mrow[t] = nm;
            lrow[t] = lrow[t]*alpha + sum;
            arow[t] = alpha;
        }
        __syncthreads();
        float al = arow[ar];
        #pragma unroll
        for (int c2 = 0; c2 < 8; ++c2) av[c2] *= al;
        for (int s = 0; s < 64; ++s) {
            float p = Ss[ar][s];
            const float* vr = &Vs[s][ae];
            #pragma unroll
            for (int c2 = 0; c2 < 8; ++c2) av[c2] += p * vr[c2];
        }
    }
    float inv = 1.0f / lrow[ar];
    __bf16* orow = o + (size_t)(b*T_ + qt*32 + ar) * D_ + h*HS_ + ae;
    #pragma unroll
    for (int c2 = 0; c2 < 8; ++c2) orow[c2] = (__bf16)(av[c2] * inv);
}

// ---------------------------------------------------------------- fp32 SGEMM (head only)
__global__ __launch_bounds__(256)
void sgemm(const float* __restrict__ A, const float* __restrict__ Bm,
           const float* __restrict__ bias, const float* __restrict__ res,
           float* __restrict__ C, int M, int N, int K,
           int hb, int hstride, int kstride, int relu)
{
    __shared__ float As[16][64];
    __shared__ float Bs[16][64];
    int tid = threadIdx.x;
    int tx = tid & 15, ty = tid >> 4;
    int m0 = blockIdx.y * 64;
    int n0 = blockIdx.x * 64;

    int bk  = tid >> 4;
    int bn0 = (tid & 15) * 4;
    int hblk[4], nn[4], nv[4];
    #pragma unroll
    for (int j = 0; j < 4; ++j) {
        int n = n0 + bn0 + j;
        nv[j]   = (n < N);
        hblk[j] = nv[j] ? (n / hb) : 0;
        nn[j]   = nv[j] ? (n % hb) : 0;
    }
    int amr = tid >> 2;
    int aks = (tid & 3) * 4;

    float acc[4][4] = {};
    for (int k0 = 0; k0 < K; k0 += 16) {
        const float4 a4 = *reinterpret_cast<const float4*>(
            A + (size_t)(m0+amr)*K + k0 + aks);
        As[aks+0][amr] = a4.x; As[aks+1][amr] = a4.y;
        As[aks+2][amr] = a4.z; As[aks+3][amr] = a4.w;
        #pragma unroll
        for (int j = 0; j < 4; ++j) {
            float vbl = 0.f;
            if (nv[j])
                vbl = Bm[(size_t)hblk[j]*hstride + (size_t)(k0+bk)*kstride + nn[j]];
            Bs[bk][bn0 + j] = vbl;
        }
        __syncthreads();
        #pragma unroll
        for (int kk = 0; kk < 16; ++kk) {
            float arr[4], br[4];
            #pragma unroll
            for (int i = 0; i < 4; ++i) arr[i] = As[kk][ty*4+i];
            #pragma unroll
            for (int j = 0; j < 4; ++j) br[j] = Bs[kk][tx*4+j];
            #pragma unroll
            for (int i = 0; i < 4; ++i)
                #pragma unroll
                for (int j = 0; j < 4; ++j)
                    acc[i][j] += arr[i]*br[j];
        }
        __syncthreads();
    }
    #pragma unroll
    for (int i = 0; i < 4; ++i) {
        int m = m0 + ty*4 + i;
        #pragma unroll
        for (int j = 0; j < 4; ++j) {
            int n = n0 + tx*4 + j;
            if (n < N) {
                float vv = acc[i][j];
                if (bias) vv += bias[n];
                if (relu) vv = fmaxf(vv, 0.f);
                if (res)  vv += res[(size_t)m*N + n];
                C[(size_t)m*N + n] = vv;
            }
        }
    }
}

// ---------------------------------------------------------------- loss
__global__ __launch_bounds__(256)
void loss_kernel(const float* __restrict__ logits,
                 const int* __restrict__ tg,
                 float* __restrict__ loss)
{
    int gid = blockIdx.x * blockDim.x + threadIdx.x;
    int row = gid >> 6;
    int lane = gid & 63;
    const float* lr = logits + (size_t)row * V_;
    float m = -INFINITY;
    for (int c = lane; c < V_; c += 64) m = fmaxf(m, lr[c]);
    for (int off = 32; off; off >>= 1) m = fmaxf(m, __shfl_xor(m, off));
    float s = 0.f;
    for (int c = lane; c < V_; c += 64) s += expf(lr[c] - m);
    for (int off = 32; off; off >>= 1) s += __shfl_xor(s, off);
    if (lane == 0) {
        float lp = lr[tg[row]] - m - logf(s);
        atomicAdd(loss, -lp * (1.0f/ROWS));
    }
}

// ---------------------------------------------------------------- launch
extern "C" void kernel_launch(void* const* d_in, const int* in_sizes, int n_in,
                              void* d_out, int out_size, void* d_ws, size_t ws_size,
                              hipStream_t stream)
{
    const int*   idx     = (const int*)  d_in[0];
    const int*   targets = (const int*)  d_in[1];
    const float* tok     = (const float*)d_in[2];
    const float* pos     = (const float*)d_in[3];
    const float* Wq      = (const float*)d_in[4];
    const float* Wk      = (const float*)d_in[5];
    const float* Wv      = (const float*)d_in[6];
    const float* Wproj   = (const float*)d_in[7];
    const float* bproj   = (const float*)d_in[8];
    const float* W1      = (const float*)d_in[9];
    const float* b1      = (const float*)d_in[10];
    const float* W2      = (const float*)d_in[11];
    const float* b2      = (const float*)d_in[12];
    const float* ln1g    = (const float*)d_in[13];
    const float* ln1b    = (const float*)d_in[14];
    const float* lnfg    = (const float*)d_in[15];
    const float* lnfb    = (const float*)d_in[16];
    const float* Whead   = (const float*)d_in[17];
    const float* bhead   = (const float*)d_in[18];

    float* logits = (float*)d_out;
    float* loss   = logits + (size_t)ROWS * V_;

    const size_t SZ = (size_t)ROWS * D_;             // 6291456
    const size_t RGELEMS = (size_t)ROWS * 4 * D_;    // 25165824 bf16 elems

    float*  x   = (float*)d_ws;                      // SZ f32
    __bf16* yb  = (__bf16*)(x + SZ);                 // SZ bf16
    __bf16* Rg  = yb + SZ;                           // RGELEMS bf16 (shared region)
    __bf16* qkv = Rg;                                // ROWS*1152 bf16 (attn phase)
    __bf16* hid = Rg;                                // ROWS*1536 bf16 (FFN phase)
    float*  yf  = (float*)Rg;                        // SZ f32 (final LN only)
    __bf16* o   = Rg + RGELEMS;                      // SZ bf16
    __bf16* qkvT  = o + SZ;                          // L*1152*384
    __bf16* projT = qkvT + (size_t)L_*QKVN*D_;       // L*384*384
    __bf16* w1T   = projT + (size_t)L_*D_*D_;        // L*1536*384
    __bf16* w2T   = w1T + (size_t)L_*D_*4*D_;        // L*384*1536

    // weight conversion (transpose to [N][K] bf16)
    transpose_cast<<<dim3(2,12,36),256,0,stream>>>(Wq, qkvT, D_, HS_, H_,
        (long)QKVN*D_, (long)HS_*D_, 0L);
    transpose_cast<<<dim3(2,12,36),256,0,stream>>>(Wk, qkvT, D_, HS_, H_,
        (long)QKVN*D_, (long)HS_*D_, (long)D_*D_);
    transpose_cast<<<dim3(2,12,36),256,0,stream>>>(Wv, qkvT, D_, HS_, H_,
        (long)QKVN*D_, (long)HS_*D_, 2L*D_*D_);
    transpose_cast<<<dim3(12,12,6),256,0,stream>>>(Wproj, projT, D_, D_, 1,
        (long)D_*D_, 0L, 0L);
    transpose_cast<<<dim3(48,12,6),256,0,stream>>>(W1, w1T, D_, 4*D_, 1,
        (long)D_*4*D_, 0L, 0L);
    transpose_cast<<<dim3(12,48,6),256,0,stream>>>(W2, w2T, 4*D_, D_, 1,
        (long)D_*4*D_, 0L, 0L);

    embed_kernel<<<(ROWS*D_)/256, 256, 0, stream>>>(idx, tok, pos, x);

    for (int l = 0; l < L_; ++l) {
        ln_kernel<<<ROWS, 128, 0, stream>>>(x, ln1g + l*D_, ln1b + l*D_, nullptr, yb);
        gemm_bf16<<<dim3(QKVN/128, ROWS/128), 256, 0, stream>>>(
            yb, qkvT + (size_t)l*QKVN*D_, nullptr, nullptr, nullptr, qkv,
            D_, QKVN, 0);
        attn2<<<B_*H_*8, 256, 0, stream>>>(qkv, o);
        gemm_bf16<<<dim3(D_/128, ROWS/128), 256, 0, stream>>>(
            o, projT + (size_t)l*D_*D_, bproj + l*D_, x, x, nullptr,
            D_, D_, 0);
        ln_kernel<<<ROWS, 128, 0, stream>>>(x, ln1g + l*D_, ln1b + l*D_, nullptr, yb);
        gemm_bf16<<<dim3(4*D_/128, ROWS/128), 256, 0, stream>>>(
            yb, w1T + (size_t)l*D_*4*D_, b1 + l*4*D_, nullptr, nullptr, hid,
            D_, 4*D_, 1);
        gemm_bf16<<<dim3(D_/128, ROWS/128), 256, 0, stream>>>(
            hid, w2T + (size_t)l*D_*4*D_, b2 + l*D_, x, x, nullptr,
            4*D_, D_, 0);
    }
    ln_kernel<<<ROWS, 128, 0, stream>>>(x, lnfg, lnfb, yf, nullptr);
    sgemm<<<dim3((V_+63)/64, ROWS/64), 256, 0, stream>>>(
        yf, Whead, bhead, nullptr, logits, ROWS, V_, D_, V_, 0, V_, 0);
    hipMemsetAsync(loss, 0, sizeof(float), stream);
    loss_kernel<<<ROWS/4, 256, 0, stream>>>(logits, targets, loss);
}

// Round 3
// 1951.782 us; speedup vs baseline: 6.1484x; 1.5479x over previous
//
#include <hip/hip_runtime.h>
#include <math.h>

#define L_ 6
#define H_ 6
#define HS_ 64
#define D_ 384
#define T_ 256
#define V_ 65
#define B_ 64
#define ROWS (B_*T_)        // 16384
#define QKVN 1152
#define EPS_ 1e-5f

typedef __attribute__((ext_vector_type(8))) __bf16 bf16x8;
typedef __attribute__((ext_vector_type(4))) float f32x4;

__device__ __forceinline__ bf16x8 u4_to_bf8(uint4 u) {
    return __builtin_bit_cast(bf16x8, u);
}

// async global->LDS, 16B per lane. lds ptr must be wave-uniform; HW scatters lane i to lds + i*16.
__device__ __forceinline__ void glds16(const void* g, void* l) {
    __builtin_amdgcn_global_load_lds(
        (const __attribute__((address_space(1))) void*)g,
        (__attribute__((address_space(3))) void*)l, 16, 0, 0);
}

// ---------------------------------------------------------------- embedding
__global__ void embed_kernel(const int* __restrict__ idx,
                             const float* __restrict__ tok,
                             const float* __restrict__ pos,
                             float* __restrict__ x) {
    int i = blockIdx.x * blockDim.x + threadIdx.x;   // < ROWS*D_
    int d = i % D_;
    int row = i / D_;
    int t = row % T_;
    x[i] = tok[idx[row]*D_ + d] + pos[t*D_ + d];
}

// ---------------------------------------------------------------- layernorm
// wave per row, 4 rows per 256-thread block. bf16 out.
__global__ __launch_bounds__(256)
void ln4(const float* __restrict__ x,
         const float* __restrict__ g,
         const float* __restrict__ b,
         __bf16* __restrict__ yb) {
    int w = threadIdx.x >> 6, lane = threadIdx.x & 63;
    int row = blockIdx.x * 4 + w;
    const float* xr = x + (size_t)row * D_;
    float v[6];
    #pragma unroll
    for (int i = 0; i < 6; ++i) v[i] = xr[lane + 64*i];
    float s = 0.f, sq = 0.f;
    #pragma unroll
    for (int i = 0; i < 6; ++i) { s += v[i]; sq += v[i]*v[i]; }
    for (int off = 32; off; off >>= 1) {
        s  += __shfl_xor(s,  off);
        sq += __shfl_xor(sq, off);
    }
    float mean = s * (1.0f/D_);
    float var  = sq * (1.0f/D_) - mean*mean;
    float rstd = rsqrtf(var + EPS_);
    __bf16* yr = yb + (size_t)row * D_;
    #pragma unroll
    for (int i = 0; i < 6; ++i) {
        int c = lane + 64*i;
        yr[c] = (__bf16)((v[i]-mean)*rstd*g[c] + b[c]);
    }
}

// ---------------------------------------------------------------- transpose+cast
__global__ __launch_bounds__(256)
void transpose_cast(const float* __restrict__ src, __bf16* __restrict__ dst,
                    int R, int C, int zdiv, long sA, long sB, long dbase)
{
    __shared__ float tile[32][33];
    int z = blockIdx.z;
    const float* s = src + (long)z * R * C;
    __bf16* d = dst + dbase + (long)(z / zdiv) * sA + (long)(z % zdiv) * sB;
    int c0 = blockIdx.x * 32, r0 = blockIdx.y * 32;
    int t = threadIdx.x;
    int tr = t >> 3, tc = (t & 7) * 4;
    float4 v = *(const float4*)(s + (long)(r0 + tr) * C + c0 + tc);
    tile[tr][tc+0] = v.x; tile[tr][tc+1] = v.y;
    tile[tr][tc+2] = v.z; tile[tr][tc+3] = v.w;
    __syncthreads();
    #pragma unroll
    for (int j = 0; j < 4; ++j)
        d[(long)(c0 + tr) * R + r0 + tc + j] = (__bf16)tile[tc+j][tr];
}

// head weight: Whead [384][65] fp32 -> headT [128][384] bf16 (zero-padded rows 65..127)
__global__ __launch_bounds__(256)
void head_prep(const float* __restrict__ Whead, __bf16* __restrict__ headT) {
    int i = blockIdx.x * 256 + threadIdx.x;   // < 128*384
    int n = i / D_, k = i % D_;
    headT[i] = (n < V_) ? (__bf16)Whead[k*V_ + n] : (__bf16)0.0f;
}

// ---------------------------------------------------------------- bf16 MFMA GEMM (m97-style)
// C[M,N] = act(A[M,K] @ Bt^T + bias) (+res);  Bt is [N][K] bf16.
// 128x128 tile, BK=32, 256 thr = 4 waves. global_load_lds dwordx4 staging.
__global__ __launch_bounds__(256)
void gemm_m97(const __bf16* __restrict__ A, const __bf16* __restrict__ Bt,
              const float* __restrict__ bias, const float* res,
              float* outF, __bf16* outB,
              int K, int ldc, int ncols, int relu)
{
    __shared__ __align__(16) __bf16 As[128*32];
    __shared__ __align__(16) __bf16 Bs[128*32];
    int t = threadIdx.x;
    int w = t >> 6, lane = t & 63;
    int ln = lane & 15, quad = lane >> 4;
    int n0 = blockIdx.x * 128, m0 = blockIdx.y * 128;
    int wm = (w >> 1) * 64, wn = (w & 1) * 64;

    f32x4 acc[4][4] = {};

    const char* Ab = (const char*)A + (size_t)m0 * K * 2;
    const char* Bb = (const char*)Bt + (size_t)n0 * K * 2;
    int f0 = w*64 + lane, f1 = f0 + 256;
    size_t ga0 = (size_t)(f0 >> 2) * K * 2 + (size_t)(f0 & 3) * 16;
    size_t ga1 = (size_t)(f1 >> 2) * K * 2 + (size_t)(f1 & 3) * 16;
    char* lA0 = (char*)As + (size_t)(w*64) * 16;
    char* lA1 = (char*)As + (size_t)(w*64 + 256) * 16;
    char* lB0 = (char*)Bs + (size_t)(w*64) * 16;
    char* lB1 = (char*)Bs + (size_t)(w*64 + 256) * 16;

    for (int k0 = 0; k0 < K; k0 += 32) {
        size_t kb = (size_t)k0 * 2;
        glds16(Ab + ga0 + kb, lA0);
        glds16(Ab + ga1 + kb, lA1);
        glds16(Bb + ga0 + kb, lB0);
        glds16(Bb + ga1 + kb, lB1);
        __syncthreads();
        bf16x8 af[4], bfr[4];
        #pragma unroll
        for (int i = 0; i < 4; ++i)
            af[i] = __builtin_bit_cast(bf16x8,
                *(const uint4*)&As[(wm + i*16 + ln)*32 + quad*8]);
        #pragma unroll
        for (int j = 0; j < 4; ++j)
            bfr[j] = __builtin_bit_cast(bf16x8,
                *(const uint4*)&Bs[(wn + j*16 + ln)*32 + quad*8]);
        #pragma unroll
        for (int i = 0; i < 4; ++i)
            #pragma unroll
            for (int j = 0; j < 4; ++j)
                acc[i][j] = __builtin_amdgcn_mfma_f32_16x16x32_bf16(
                                af[i], bfr[j], acc[i][j], 0, 0, 0);
        __syncthreads();
    }
    #pragma unroll
    for (int i = 0; i < 4; ++i) {
        #pragma unroll
        for (int r = 0; r < 4; ++r) {
            int row = m0 + wm + i*16 + quad*4 + r;
            #pragma unroll
            for (int j = 0; j < 4; ++j) {
                int col = n0 + wn + j*16 + ln;
                if (col < ncols) {
                    float v = acc[i][j][r];
                    if (bias) v += bias[col];
                    if (relu) v = fmaxf(v, 0.f);
                    if (res)  v += res[(size_t)row*ldc + col];
                    if (outF) outF[(size_t)row*ldc + col] = v;
                    if (outB) outB[(size_t)row*ldc + col] = (__bf16)v;
                }
            }
        }
    }
}

// ---------------------------------------------------------------- MFMA flash attention
// one block per (b,h); wave w owns q rows [w*64, w*64+64) and s-tiles 0..w (causal).
// K staged [256][72] LDS, V transposed [64][264] LDS, P round-trips per-wave [64][72].
__global__ __launch_bounds__(256, 1)
void attn3(const __bf16* __restrict__ qkv, __bf16* __restrict__ o)
{
    __shared__ __align__(16) __bf16 Ks[256*72];
    __shared__ __align__(16) __bf16 Vt[64*264];
    __shared__ __align__(16) __bf16 Pw[4][64*72];
    int bid = blockIdx.x;
    int h = bid % H_;
    int b = bid / H_;
    int t = threadIdx.x;
    int w = t >> 6, lane = t & 63;
    int ln = lane & 15, quad = lane >> 4;
    const size_t rowb = (size_t)b * T_ * QKVN;
    const int hoff = h * HS_;
    const float scale = 0.05103103630798288f;   // 1/sqrt(384)

    // stage K and V^T
    for (int c = t; c < 2048; c += 256) {
        int r = c >> 3, e0 = (c & 7) * 8;
        uint4 uk = *(const uint4*)(qkv + rowb + (size_t)r*QKVN + 384 + hoff + e0);
        *(uint4*)&Ks[r*72 + e0] = uk;
        uint4 uv = *(const uint4*)(qkv + rowb + (size_t)r*QKVN + 768 + hoff + e0);
        bf16x8 v8 = u4_to_bf8(uv);
        #pragma unroll
        for (int j = 0; j < 8; ++j) Vt[(e0+j)*264 + r] = v8[j];
    }

    // Q fragments in registers (A-layout: m=ln, k=quad*8+j)
    int qb = w * 64;
    uint4 Qf[4][2];
    #pragma unroll
    for (int mi = 0; mi < 4; ++mi)
        #pragma unroll
        for (int kc = 0; kc < 2; ++kc)
            Qf[mi][kc] = *(const uint4*)(qkv + rowb +
                (size_t)(qb + mi*16 + ln)*QKVN + hoff + kc*32 + quad*8);

    __syncthreads();

    f32x4 O[4][4] = {};
    float mst[4][4], lst[4][4];
    #pragma unroll
    for (int i = 0; i < 4; ++i)
        #pragma unroll
        for (int r = 0; r < 4; ++r) { mst[i][r] = -INFINITY; lst[i][r] = 0.f; }

    for (int st = 0; st <= w; ++st) {
        int sb = st * 64;
        // S = Q K^T
        f32x4 S[4][4] = {};
        #pragma unroll
        for (int kc = 0; kc < 2; ++kc) {
            uint4 Kf[4];
            #pragma unroll
            for (int ji = 0; ji < 4; ++ji)
                Kf[ji] = *(const uint4*)&Ks[(sb + ji*16 + ln)*72 + kc*32 + quad*8];
            #pragma unroll
            for (int mi = 0; mi < 4; ++mi) {
                bf16x8 qa = __builtin_bit_cast(bf16x8, Qf[mi][kc]);
                #pragma unroll
                for (int ji = 0; ji < 4; ++ji)
                    S[mi][ji] = __builtin_amdgcn_mfma_f32_16x16x32_bf16(
                        qa, __builtin_bit_cast(bf16x8, Kf[ji]), S[mi][ji], 0, 0, 0);
            }
        }
        // scale + causal mask (C layout: row=quad*4+r, col=ln per 16x16 tile)
        int diag = (st == w);
        #pragma unroll
        for (int mi = 0; mi < 4; ++mi)
            #pragma unroll
            for (int ji = 0; ji < 4; ++ji)
                #pragma unroll
                for (int r = 0; r < 4; ++r) {
                    float v = S[mi][ji][r] * scale;
                    if (diag && (ji*16 + ln) > (mi*16 + quad*4 + r)) v = -INFINITY;
                    S[mi][ji][r] = v;
                }
        // online softmax per row (rows live in 16-lane groups)
        #pragma unroll
        for (int mi = 0; mi < 4; ++mi)
            #pragma unroll
            for (int r = 0; r < 4; ++r) {
                float mx = fmaxf(fmaxf(S[mi][0][r], S[mi][1][r]),
                                 fmaxf(S[mi][2][r], S[mi][3][r]));
                #pragma unroll
                for (int off = 1; off < 16; off <<= 1)
                    mx = fmaxf(mx, __shfl_xor(mx, off));
                float mn = fmaxf(mst[mi][r], mx);
                float al = __expf(mst[mi][r] - mn);
                mst[mi][r] = mn;
                float rs = 0.f;
                #pragma unroll
                for (int ji = 0; ji < 4; ++ji) {
                    float p = __expf(S[mi][ji][r] - mn);
                    S[mi][ji][r] = p;
                    rs += p;
                }
                #pragma unroll
                for (int off = 1; off < 16; off <<= 1)
                    rs += __shfl_xor(rs, off);
                lst[mi][r] = lst[mi][r]*al + rs;
                #pragma unroll
                for (int ei = 0; ei < 4; ++ei) O[mi][ei][r] *= al;
            }
        // P (C layout) -> LDS -> A layout
        __bf16* P = Pw[w];
        #pragma unroll
        for (int mi = 0; mi < 4; ++mi)
            #pragma unroll
            for (int ji = 0; ji < 4; ++ji)
                #pragma unroll
                for (int r = 0; r < 4; ++r)
                    P[(mi*16 + quad*4 + r)*72 + ji*16 + ln] = (__bf16)S[mi][ji][r];
        // O += P V
        #pragma unroll
        for (int kc = 0; kc < 2; ++kc) {
            uint4 Pf[4], Vf[4];
            #pragma unroll
            for (int mi = 0; mi < 4; ++mi)
                Pf[mi] = *(const uint4*)&P[(mi*16 + ln)*72 + kc*32 + quad*8];
            #pragma unroll
            for (int ei = 0; ei < 4; ++ei)
                Vf[ei] = *(const uint4*)&Vt[(ei*16 + ln)*264 + sb + kc*32 + quad*8];
            #pragma unroll
            for (int mi = 0; mi < 4; ++mi)
                #pragma unroll
                for (int ei = 0; ei < 4; ++ei)
                    O[mi][ei] = __builtin_amdgcn_mfma_f32_16x16x32_bf16(
                        __builtin_bit_cast(bf16x8, Pf[mi]),
                        __builtin_bit_cast(bf16x8, Vf[ei]), O[mi][ei], 0, 0, 0);
        }
    }
    // epilogue: O / l -> o [ROWS][384]
    #pragma unroll
    for (int mi = 0; mi < 4; ++mi)
        #pragma unroll
        for (int r = 0; r < 4; ++r) {
            float inv = 1.0f / lst[mi][r];
            size_t row = (size_t)(b*T_ + qb + mi*16 + quad*4 + r);
            #pragma unroll
            for (int ei = 0; ei < 4; ++ei)
                o[row*D_ + hoff + ei*16 + ln] = (__bf16)(O[mi][ei][r] * inv);
        }
}

// ---------------------------------------------------------------- loss
// one thread per row; block-reduce; one atomic per 256 rows.
__global__ __launch_bounds__(256)
void loss2(const float* __restrict__ logits,
           const int* __restrict__ tg,
           float* __restrict__ loss)
{
    int row = blockIdx.x * 256 + threadIdx.x;
    const float* lr = logits + (size_t)row * V_;
    float m = -INFINITY;
    for (int c = 0; c < V_; ++c) m = fmaxf(m, lr[c]);
    float s = 0.f;
    for (int c = 0; c < V_; ++c) s += __expf(lr[c] - m);
    float val = -(lr[tg[row]] - m - __logf(s)) * (1.0f/ROWS);
    for (int off = 32; off; off >>= 1) val += __shfl_xor(val, off);
    __shared__ float red[4];
    int w = threadIdx.x >> 6, lane = threadIdx.x & 63;
    if (lane == 0) red[w] = val;
    __syncthreads();
    if (threadIdx.x == 0)
        atomicAdd(loss, red[0]+red[1]+red[2]+red[3]);
}

// ---------------------------------------------------------------- launch
extern "C" void kernel_launch(void* const* d_in, const int* in_sizes, int n_in,
                              void* d_out, int out_size, void* d_ws, size_t ws_size,
                              hipStream_t stream)
{
    const int*   idx     = (const int*)  d_in[0];
    const int*   targets = (const int*)  d_in[1];
    const float* tok     = (const float*)d_in[2];
    const float* pos     = (const float*)d_in[3];
    const float* Wq      = (const float*)d_in[4];
    const float* Wk      = (const float*)d_in[5];
    const float* Wv      = (const float*)d_in[6];
    const float* Wproj   = (const float*)d_in[7];
    const float* bproj   = (const float*)d_in[8];
    const float* W1      = (const float*)d_in[9];
    const float* b1      = (const float*)d_in[10];
    const float* W2      = (const float*)d_in[11];
    const float* b2      = (const float*)d_in[12];
    const float* ln1g    = (const float*)d_in[13];
    const float* ln1b    = (const float*)d_in[14];
    const float* lnfg    = (const float*)d_in[15];
    const float* lnfb    = (const float*)d_in[16];
    const float* Whead   = (const float*)d_in[17];
    const float* bhead   = (const float*)d_in[18];

    float* logits = (float*)d_out;
    float* loss   = logits + (size_t)ROWS * V_;

    const size_t SZ = (size_t)ROWS * D_;             // 6291456
    const size_t RGELEMS = (size_t)ROWS * 4 * D_;    // 25165824 bf16 elems

    float*  x   = (float*)d_ws;                      // SZ f32
    __bf16* yb  = (__bf16*)(x + SZ);                 // SZ bf16
    __bf16* Rg  = yb + SZ;                           // RGELEMS bf16 (qkv / hid)
    __bf16* qkv = Rg;                                // ROWS*1152
    __bf16* hid = Rg;                                // ROWS*1536
    __bf16* o   = Rg + RGELEMS;                      // SZ bf16
    __bf16* qkvT  = o + SZ;                          // L*1152*384
    __bf16* projT = qkvT + (size_t)L_*QKVN*D_;       // L*384*384
    __bf16* w1T   = projT + (size_t)L_*D_*D_;        // L*1536*384
    __bf16* w2T   = w1T + (size_t)L_*D_*4*D_;        // L*384*1536
    __bf16* headT = w2T + (size_t)L_*D_*4*D_;        // 128*384

    // weight conversion (transpose to [N][K] bf16)
    transpose_cast<<<dim3(2,12,36),256,0,stream>>>(Wq, qkvT, D_, HS_, H_,
        (long)QKVN*D_, (long)HS_*D_, 0L);
    transpose_cast<<<dim3(2,12,36),256,0,stream>>>(Wk, qkvT, D_, HS_, H_,
        (long)QKVN*D_, (long)HS_*D_, (long)D_*D_);
    transpose_cast<<<dim3(2,12,36),256,0,stream>>>(Wv, qkvT, D_, HS_, H_,
        (long)QKVN*D_, (long)HS_*D_, 2L*D_*D_);
    transpose_cast<<<dim3(12,12,6),256,0,stream>>>(Wproj, projT, D_, D_, 1,
        (long)D_*D_, 0L, 0L);
    transpose_cast<<<dim3(48,12,6),256,0,stream>>>(W1, w1T, D_, 4*D_, 1,
        (long)D_*4*D_, 0L, 0L);
    transpose_cast<<<dim3(12,48,6),256,0,stream>>>(W2, w2T, 4*D_, D_, 1,
        (long)D_*4*D_, 0L, 0L);
    head_prep<<<(128*D_)/256, 256, 0, stream>>>(Whead, headT);

    embed_kernel<<<(ROWS*D_)/256, 256, 0, stream>>>(idx, tok, pos, x);

    for (int l = 0; l < L_; ++l) {
        ln4<<<ROWS/4, 256, 0, stream>>>(x, ln1g + l*D_, ln1b + l*D_, yb);
        gemm_m97<<<dim3(QKVN/128, ROWS/128), 256, 0, stream>>>(
            yb, qkvT + (size_t)l*QKVN*D_, nullptr, nullptr, nullptr, qkv,
            D_, QKVN, QKVN, 0);
        attn3<<<B_*H_, 256, 0, stream>>>(qkv, o);
        gemm_m97<<<dim3(D_/128, ROWS/128), 256, 0, stream>>>(
            o, projT + (size_t)l*D_*D_, bproj + l*D_, x, x, nullptr,
            D_, D_, D_, 0);
        ln4<<<ROWS/4, 256, 0, stream>>>(x, ln1g + l*D_, ln1b + l*D_, yb);
        gemm_m97<<<dim3(4*D_/128, ROWS/128), 256, 0, stream>>>(
            yb, w1T + (size_t)l*D_*4*D_, b1 + l*4*D_, nullptr, nullptr, hid,
            D_, 4*D_, 4*D_, 1);
        gemm_m97<<<dim3(D_/128, ROWS/128), 256, 0, stream>>>(
            hid, w2T + (size_t)l*D_*4*D_, b2 + l*D_, x, x, nullptr,
            4*D_, D_, D_, 0);
    }
    ln4<<<ROWS/4, 256, 0, stream>>>(x, lnfg, lnfb, yb);
    gemm_m97<<<dim3(1, ROWS/128), 256, 0, stream>>>(
        yb, headT, bhead, nullptr, logits, nullptr,
        D_, V_, V_, 0);
    hipMemsetAsync(loss, 0, sizeof(float), stream);
    loss2<<<ROWS/256, 256, 0, stream>>>(logits, targets, loss);
}

// Round 4
// 1731.366 us; speedup vs baseline: 6.9311x; 1.1273x over previous
//
#include <hip/hip_runtime.h>
#include <math.h>

#define L_ 6
#define H_ 6
#define HS_ 64
#define D_ 384
#define T_ 256
#define V_ 65
#define B_ 64
#define ROWS (B_*T_)        // 16384
#define QKVN 1152
#define EPS_ 1e-5f

typedef __attribute__((ext_vector_type(8))) __bf16 bf16x8;
typedef __attribute__((ext_vector_type(4))) float f32x4;

__device__ __forceinline__ bf16x8 u4_to_bf8(uint4 u) {
    return __builtin_bit_cast(bf16x8, u);
}

// async global->LDS, 16B per lane. lds ptr wave-uniform; HW scatters lane i to lds + i*16.
__device__ __forceinline__ void glds16(const void* g, void* l) {
    __builtin_amdgcn_global_load_lds(
        (const __attribute__((address_space(1))) void*)g,
        (__attribute__((address_space(3))) void*)l, 16, 0, 0);
}

// ---------------------------------------------------------------- embedding
__global__ void embed_kernel(const int* __restrict__ idx,
                             const float* __restrict__ tok,
                             const float* __restrict__ pos,
                             float* __restrict__ x) {
    int i = blockIdx.x * blockDim.x + threadIdx.x;   // < ROWS*D_
    int d = i % D_;
    int row = i / D_;
    int t = row % T_;
    x[i] = tok[idx[row]*D_ + d] + pos[t*D_ + d];
}

// ---------------------------------------------------------------- layernorm
// wave per row, 4 rows per 256-thread block. bf16 out.
__global__ __launch_bounds__(256)
void ln4(const float* __restrict__ x,
         const float* __restrict__ g,
         const float* __restrict__ b,
         __bf16* __restrict__ yb) {
    int w = threadIdx.x >> 6, lane = threadIdx.x & 63;
    int row = blockIdx.x * 4 + w;
    const float* xr = x + (size_t)row * D_;
    float v[6];
    #pragma unroll
    for (int i = 0; i < 6; ++i) v[i] = xr[lane + 64*i];
    float s = 0.f, sq = 0.f;
    #pragma unroll
    for (int i = 0; i < 6; ++i) { s += v[i]; sq += v[i]*v[i]; }
    for (int off = 32; off; off >>= 1) {
        s  += __shfl_xor(s,  off);
        sq += __shfl_xor(sq, off);
    }
    float mean = s * (1.0f/D_);
    float var  = sq * (1.0f/D_) - mean*mean;
    float rstd = rsqrtf(var + EPS_);
    __bf16* yr = yb + (size_t)row * D_;
    #pragma unroll
    for (int i = 0; i < 6; ++i) {
        int c = lane + 64*i;
        yr[c] = (__bf16)((v[i]-mean)*rstd*g[c] + b[c]);
    }
}

// ---------------------------------------------------------------- transpose+cast
__global__ __launch_bounds__(256)
void transpose_cast(const float* __restrict__ src, __bf16* __restrict__ dst,
                    int R, int C, int zdiv, long sA, long sB, long dbase)
{
    __shared__ float tile[32][33];
    int z = blockIdx.z;
    const float* s = src + (long)z * R * C;
    __bf16* d = dst + dbase + (long)(z / zdiv) * sA + (long)(z % zdiv) * sB;
    int c0 = blockIdx.x * 32, r0 = blockIdx.y * 32;
    int t = threadIdx.x;
    int tr = t >> 3, tc = (t & 7) * 4;
    float4 v = *(const float4*)(s + (long)(r0 + tr) * C + c0 + tc);
    tile[tr][tc+0] = v.x; tile[tr][tc+1] = v.y;
    tile[tr][tc+2] = v.z; tile[tr][tc+3] = v.w;
    __syncthreads();
    #pragma unroll
    for (int j = 0; j < 4; ++j)
        d[(long)(c0 + tr) * R + r0 + tc + j] = (__bf16)tile[tc+j][tr];
}

// head weight: Whead [384][65] fp32 -> headT [128][384] bf16 (zero-padded rows 65..127)
__global__ __launch_bounds__(256)
void head_prep(const float* __restrict__ Whead, __bf16* __restrict__ headT) {
    int i = blockIdx.x * 256 + threadIdx.x;   // < 128*384
    int n = i / D_, k = i % D_;
    headT[i] = (n < V_) ? (__bf16)Whead[k*V_ + n] : (__bf16)0.0f;
}

// ---------------------------------------------------------------- bf16 MFMA GEMM
// double-buffered LDS + XOR bank swizzle.
// C[M,N] = act(A[M,K] @ Bt^T + bias) (+res);  Bt is [N][K] bf16.
// 128x128 tile, BK=32, 256 thr = 4 waves.
__global__ __launch_bounds__(256)
void gemm_db(const __bf16* __restrict__ A, const __bf16* __restrict__ Bt,
             const float* __restrict__ bias, const float* res,
             float* outF, __bf16* outB,
             int K, int ldc, int ncols, int relu)
{
    __shared__ __align__(16) __bf16 As[2][128*32];
    __shared__ __align__(16) __bf16 Bs[2][128*32];
    int t = threadIdx.x;
    int w = t >> 6, lane = t & 63;
    int ln = lane & 15, quad = lane >> 4;
    int n0 = blockIdx.x * 128, m0 = blockIdx.y * 128;
    int wm = (w >> 1) * 64, wn = (w & 1) * 64;

    f32x4 acc[4][4] = {};

    const char* Ab = (const char*)A + (size_t)m0 * K * 2;
    const char* Bb = (const char*)Bt + (size_t)n0 * K * 2;
    int f0 = w*64 + lane, f1 = f0 + 256;
    int r0 = f0 >> 2, r1 = f1 >> 2;
    // swizzled source chunk within the row's 64B (keeps coalescing, breaks LDS banks)
    size_t ga0 = (size_t)r0 * K * 2 + (size_t)(((f0 & 3) ^ (r0 & 3)) * 16);
    size_t ga1 = (size_t)r1 * K * 2 + (size_t)(((f1 & 3) ^ (r1 & 3)) * 16);
    int lo0 = w*64*16, lo1 = (w*64 + 256)*16;

    int nIt = K >> 5;
    // prologue: stage k=0 into buffer 0
    glds16(Ab + ga0, (char*)As[0] + lo0);
    glds16(Ab + ga1, (char*)As[0] + lo1);
    glds16(Bb + ga0, (char*)Bs[0] + lo0);
    glds16(Bb + ga1, (char*)Bs[0] + lo1);

    for (int it = 0; it < nIt; ++it) {
        int p = it & 1;
        __syncthreads();               // drains staging of buf p (prefetched last iter)
        if (it + 1 < nIt) {            // prefetch k+1 into buf p^1 (in flight during MFMA)
            size_t kb = (size_t)(it + 1) * 64;
            glds16(Ab + ga0 + kb, (char*)As[p^1] + lo0);
            glds16(Ab + ga1 + kb, (char*)As[p^1] + lo1);
            glds16(Bb + ga0 + kb, (char*)Bs[p^1] + lo0);
            glds16(Bb + ga1 + kb, (char*)Bs[p^1] + lo1);
        }
        bf16x8 af[4], bfr[4];
        #pragma unroll
        for (int i = 0; i < 4; ++i) {
            int row = wm + i*16 + ln;
            af[i] = __builtin_bit_cast(bf16x8,
                *(const uint4*)&As[p][row*32 + ((quad ^ (row & 3)) * 8)]);
        }
        #pragma unroll
        for (int j = 0; j < 4; ++j) {
            int row = wn + j*16 + ln;
            bfr[j] = __builtin_bit_cast(bf16x8,
                *(const uint4*)&Bs[p][row*32 + ((quad ^ (row & 3)) * 8)]);
        }
        #pragma unroll
        for (int i = 0; i < 4; ++i)
            #pragma unroll
            for (int j = 0; j < 4; ++j)
                acc[i][j] = __builtin_amdgcn_mfma_f32_16x16x32_bf16(
                                af[i], bfr[j], acc[i][j], 0, 0, 0);
        __syncthreads();
    }
    #pragma unroll
    for (int i = 0; i < 4; ++i) {
        #pragma unroll
        for (int r = 0; r < 4; ++r) {
            int row = m0 + wm + i*16 + quad*4 + r;
            #pragma unroll
            for (int j = 0; j < 4; ++j) {
                int col = n0 + wn + j*16 + ln;
                if (col < ncols) {
                    float v = acc[i][j][r];
                    if (bias) v += bias[col];
                    if (relu) v = fmaxf(v, 0.f);
                    if (res)  v += res[(size_t)row*ldc + col];
                    if (outF) outF[(size_t)row*ldc + col] = v;
                    if (outB) outB[(size_t)row*ldc + col] = (__bf16)v;
                }
            }
        }
    }
}

// ---------------------------------------------------------------- MFMA flash attention
// one block per (b,h); 32-row q-tiles; wave w owns q-tiles {w, 7-w} (9 s-subtiles each).
// K [256][72] LDS; V^T bank-swizzled [64 e][264 s]; per-wave P [32][40]. ~81KB -> 2 blocks/CU.
__global__ __launch_bounds__(256, 2)
void attn4(const __bf16* __restrict__ qkv, __bf16* __restrict__ o)
{
    __shared__ __align__(16) __bf16 Ks[256*72];
    __shared__ __align__(16) __bf16 Vt[64*264];
    __shared__ __align__(16) __bf16 Pw[4][32*40];
    int bid = blockIdx.x;
    int h = bid % H_;
    int b = bid / H_;
    int t = threadIdx.x;
    int w = t >> 6, lane = t & 63;
    int ln = lane & 15, quad = lane >> 4;
    const size_t rowb = (size_t)b * T_ * QKVN;
    const int hoff = h * HS_;
    const float scale = 0.05103103630798288f;   // 1/sqrt(384)

    // stage K rows + swizzled V^T: elem (e, s) at Vt[e*264 + ((s>>3)^((e>>3)&3))*8 + (s&7)]
    for (int c = t; c < 2048; c += 256) {
        int r = c >> 3, e0 = (c & 7) * 8;
        uint4 uk = *(const uint4*)(qkv + rowb + (size_t)r*QKVN + 384 + hoff + e0);
        *(uint4*)&Ks[r*72 + e0] = uk;
        uint4 uv = *(const uint4*)(qkv + rowb + (size_t)r*QKVN + 768 + hoff + e0);
        bf16x8 v8 = u4_to_bf8(uv);
        #pragma unroll
        for (int j = 0; j < 8; ++j) {
            int e = e0 + j;
            Vt[e*264 + (((r >> 3) ^ ((e >> 3) & 3)) * 8) + (r & 7)] = v8[j];
        }
    }

    // Q fragments for both q-tiles (A-layout: m=ln, k=quad*8+j)
    int qis[2] = { w, 7 - w };
    uint4 Qf[2][2][2];
    #pragma unroll
    for (int tl = 0; tl < 2; ++tl)
        #pragma unroll
        for (int mi = 0; mi < 2; ++mi)
            #pragma unroll
            for (int kc = 0; kc < 2; ++kc)
                Qf[tl][mi][kc] = *(const uint4*)(qkv + rowb +
                    (size_t)(qis[tl]*32 + mi*16 + ln)*QKVN + hoff + kc*32 + quad*8);

    __syncthreads();

    __bf16* P = Pw[w];
    #pragma unroll
    for (int tl = 0; tl < 2; ++tl) {
        int qi = qis[tl];
        f32x4 O[2][4] = {};
        float mst[2][4], lst[2][4];
        #pragma unroll
        for (int mi = 0; mi < 2; ++mi)
            #pragma unroll
            for (int r = 0; r < 4; ++r) { mst[mi][r] = -INFINITY; lst[mi][r] = 0.f; }

        for (int st = 0; st <= qi; ++st) {
            int sb = st * 32;
            f32x4 S[2][2] = {};
            #pragma unroll
            for (int kc = 0; kc < 2; ++kc) {
                uint4 Kf[2];
                #pragma unroll
                for (int ji = 0; ji < 2; ++ji)
                    Kf[ji] = *(const uint4*)&Ks[(sb + ji*16 + ln)*72 + kc*32 + quad*8];
                #pragma unroll
                for (int mi = 0; mi < 2; ++mi) {
                    bf16x8 qa = __builtin_bit_cast(bf16x8, Qf[tl][mi][kc]);
                    #pragma unroll
                    for (int ji = 0; ji < 2; ++ji)
                        S[mi][ji] = __builtin_amdgcn_mfma_f32_16x16x32_bf16(
                            qa, __builtin_bit_cast(bf16x8, Kf[ji]), S[mi][ji], 0, 0, 0);
                }
            }
            int diag = (st == qi);
            #pragma unroll
            for (int mi = 0; mi < 2; ++mi)
                #pragma unroll
                for (int ji = 0; ji < 2; ++ji)
                    #pragma unroll
                    for (int r = 0; r < 4; ++r) {
                        float v = S[mi][ji][r] * scale;
                        if (diag && (ji*16 + ln) > (mi*16 + quad*4 + r)) v = -INFINITY;
                        S[mi][ji][r] = v;
                    }
            // online softmax per row (cols spread over 16-lane group)
            #pragma unroll
            for (int mi = 0; mi < 2; ++mi)
                #pragma unroll
                for (int r = 0; r < 4; ++r) {
                    float mx = fmaxf(S[mi][0][r], S[mi][1][r]);
                    #pragma unroll
                    for (int off = 1; off < 16; off <<= 1)
                        mx = fmaxf(mx, __shfl_xor(mx, off));
                    float mn = fmaxf(mst[mi][r], mx);
                    float al = __expf(mst[mi][r] - mn);
                    mst[mi][r] = mn;
                    float p0 = __expf(S[mi][0][r] - mn);
                    float p1 = __expf(S[mi][1][r] - mn);
                    S[mi][0][r] = p0; S[mi][1][r] = p1;
                    float rs = p0 + p1;
                    #pragma unroll
                    for (int off = 1; off < 16; off <<= 1)
                        rs += __shfl_xor(rs, off);
                    lst[mi][r] = lst[mi][r]*al + rs;
                    #pragma unroll
                    for (int ei = 0; ei < 4; ++ei) O[mi][ei][r] *= al;
                }
            // P (C layout) -> per-wave LDS -> A layout
            #pragma unroll
            for (int mi = 0; mi < 2; ++mi)
                #pragma unroll
                for (int ji = 0; ji < 2; ++ji)
                    #pragma unroll
                    for (int r = 0; r < 4; ++r)
                        P[(mi*16 + quad*4 + r)*40 + ji*16 + ln] = (__bf16)S[mi][ji][r];
            uint4 Pf[2], Vf[4];
            #pragma unroll
            for (int mi = 0; mi < 2; ++mi)
                Pf[mi] = *(const uint4*)&P[(mi*16 + ln)*40 + quad*8];
            #pragma unroll
            for (int ei = 0; ei < 4; ++ei) {
                int e = ei*16 + ln;
                Vf[ei] = *(const uint4*)&Vt[e*264 + (((st*4 + quad) ^ ((e >> 3) & 3)) * 8)];
            }
            #pragma unroll
            for (int mi = 0; mi < 2; ++mi)
                #pragma unroll
                for (int ei = 0; ei < 4; ++ei)
                    O[mi][ei] = __builtin_amdgcn_mfma_f32_16x16x32_bf16(
                        __builtin_bit_cast(bf16x8, Pf[mi]),
                        __builtin_bit_cast(bf16x8, Vf[ei]), O[mi][ei], 0, 0, 0);
        }
        // epilogue for this q-tile
        #pragma unroll
        for (int mi = 0; mi < 2; ++mi)
            #pragma unroll
            for (int r = 0; r < 4; ++r) {
                float inv = 1.0f / lst[mi][r];
                size_t row = (size_t)(b*T_ + qi*32 + mi*16 + quad*4 + r);
                #pragma unroll
                for (int ei = 0; ei < 4; ++ei)
                    o[row*D_ + hoff + ei*16 + ln] = (__bf16)(O[mi][ei][r] * inv);
            }
    }
}

// ---------------------------------------------------------------- loss
__global__ __launch_bounds__(256)
void loss2(const float* __restrict__ logits,
           const int* __restrict__ tg,
           float* __restrict__ loss)
{
    int row = blockIdx.x * 256 + threadIdx.x;
    const float* lr = logits + (size_t)row * V_;
    float m = -INFINITY;
    for (int c = 0; c < V_; ++c) m = fmaxf(m, lr[c]);
    float s = 0.f;
    for (int c = 0; c < V_; ++c) s += __expf(lr[c] - m);
    float val = -(lr[tg[row]] - m - __logf(s)) * (1.0f/ROWS);
    for (int off = 32; off; off >>= 1) val += __shfl_xor(val, off);
    __shared__ float red[4];
    int w = threadIdx.x >> 6, lane = threadIdx.x & 63;
    if (lane == 0) red[w] = val;
    __syncthreads();
    if (threadIdx.x == 0)
        atomicAdd(loss, red[0]+red[1]+red[2]+red[3]);
}

// ---------------------------------------------------------------- launch
extern "C" void kernel_launch(void* const* d_in, const int* in_sizes, int n_in,
                              void* d_out, int out_size, void* d_ws, size_t ws_size,
                              hipStream_t stream)
{
    const int*   idx     = (const int*)  d_in[0];
    const int*   targets = (const int*)  d_in[1];
    const float* tok     = (const float*)d_in[2];
    const float* pos     = (const float*)d_in[3];
    const float* Wq      = (const float*)d_in[4];
    const float* Wk      = (const float*)d_in[5];
    const float* Wv      = (const float*)d_in[6];
    const float* Wproj   = (const float*)d_in[7];
    const float* bproj   = (const float*)d_in[8];
    const float* W1      = (const float*)d_in[9];
    const float* b1      = (const float*)d_in[10];
    const float* W2      = (const float*)d_in[11];
    const float* b2      = (const float*)d_in[12];
    const float* ln1g    = (const float*)d_in[13];
    const float* ln1b    = (const float*)d_in[14];
    const float* lnfg    = (const float*)d_in[15];
    const float* lnfb    = (const float*)d_in[16];
    const float* Whead   = (const float*)d_in[17];
    const float* bhead   = (const float*)d_in[18];

    float* logits = (float*)d_out;
    float* loss   = logits + (size_t)ROWS * V_;

    const size_t SZ = (size_t)ROWS * D_;             // 6291456
    const size_t RGELEMS = (size_t)ROWS * 4 * D_;    // 25165824 bf16 elems

    float*  x   = (float*)d_ws;                      // SZ f32
    __bf16* yb  = (__bf16*)(x + SZ);                 // SZ bf16
    __bf16* Rg  = yb + SZ;                           // RGELEMS bf16 (qkv / hid)
    __bf16* qkv = Rg;                                // ROWS*1152
    __bf16* hid = Rg;                                // ROWS*1536
    __bf16* o   = Rg + RGELEMS;                      // SZ bf16
    __bf16* qkvT  = o + SZ;                          // L*1152*384
    __bf16* projT = qkvT + (size_t)L_*QKVN*D_;       // L*384*384
    __bf16* w1T   = projT + (size_t)L_*D_*D_;        // L*1536*384
    __bf16* w2T   = w1T + (size_t)L_*D_*4*D_;        // L*384*1536
    __bf16* headT = w2T + (size_t)L_*D_*4*D_;        // 128*384

    // weight conversion (transpose to [N][K] bf16)
    transpose_cast<<<dim3(2,12,36),256,0,stream>>>(Wq, qkvT, D_, HS_, H_,
        (long)QKVN*D_, (long)HS_*D_, 0L);
    transpose_cast<<<dim3(2,12,36),256,0,stream>>>(Wk, qkvT, D_, HS_, H_,
        (long)QKVN*D_, (long)HS_*D_, (long)D_*D_);
    transpose_cast<<<dim3(2,12,36),256,0,stream>>>(Wv, qkvT, D_, HS_, H_,
        (long)QKVN*D_, (long)HS_*D_, 2L*D_*D_);
    transpose_cast<<<dim3(12,12,6),256,0,stream>>>(Wproj, projT, D_, D_, 1,
        (long)D_*D_, 0L, 0L);
    transpose_cast<<<dim3(48,12,6),256,0,stream>>>(W1, w1T, D_, 4*D_, 1,
        (long)D_*4*D_, 0L, 0L);
    transpose_cast<<<dim3(12,48,6),256,0,stream>>>(W2, w2T, 4*D_, D_, 1,
        (long)D_*4*D_, 0L, 0L);
    head_prep<<<(128*D_)/256, 256, 0, stream>>>(Whead, headT);

    embed_kernel<<<(ROWS*D_)/256, 256, 0, stream>>>(idx, tok, pos, x);

    for (int l = 0; l < L_; ++l) {
        ln4<<<ROWS/4, 256, 0, stream>>>(x, ln1g + l*D_, ln1b + l*D_, yb);
        gemm_db<<<dim3(QKVN/128, ROWS/128), 256, 0, stream>>>(
            yb, qkvT + (size_t)l*QKVN*D_, nullptr, nullptr, nullptr, qkv,
            D_, QKVN, QKVN, 0);
        attn4<<<B_*H_, 256, 0, stream>>>(qkv, o);
        gemm_db<<<dim3(D_/128, ROWS/128), 256, 0, stream>>>(
            o, projT + (size_t)l*D_*D_, bproj + l*D_, x, x, nullptr,
            D_, D_, D_, 0);
        ln4<<<ROWS/4, 256, 0, stream>>>(x, ln1g + l*D_, ln1b + l*D_, yb);
        gemm_db<<<dim3(4*D_/128, ROWS/128), 256, 0, stream>>>(
            yb, w1T + (size_t)l*D_*4*D_, b1 + l*4*D_, nullptr, nullptr, hid,
            D_, 4*D_, 4*D_, 1);
        gemm_db<<<dim3(D_/128, ROWS/128), 256, 0, stream>>>(
            hid, w2T + (size_t)l*D_*4*D_, b2 + l*D_, x, x, nullptr,
            4*D_, D_, D_, 0);
    }
    ln4<<<ROWS/4, 256, 0, stream>>>(x, lnfg, lnfb, yb);
    gemm_db<<<dim3(1, ROWS/128), 256, 0, stream>>>(
        yb, headT, bhead, nullptr, logits, nullptr,
        D_, V_, V_, 0);
    hipMemsetAsync(loss, 0, sizeof(float), stream);
    loss2<<<ROWS/256, 256, 0, stream>>>(logits, targets, loss);
}

// Round 5
// 1529.439 us; speedup vs baseline: 7.8462x; 1.1320x over previous
//
#include <hip/hip_runtime.h>
#include <math.h>

#define L_ 6
#define H_ 6
#define HS_ 64
#define D_ 384
#define T_ 256
#define V_ 65
#define B_ 64
#define ROWS (B_*T_)        // 16384
#define QKVN 1152
#define EPS_ 1e-5f

typedef __attribute__((ext_vector_type(8))) __bf16 bf16x8;
typedef __attribute__((ext_vector_type(4))) float f32x4;

__device__ __forceinline__ bf16x8 u4_to_bf8(uint4 u) {
    return __builtin_bit_cast(bf16x8, u);
}

// async global->LDS, 16B per lane. lds ptr wave-uniform; HW scatters lane i to lds + i*16.
__device__ __forceinline__ void glds16(const void* g, void* l) {
    __builtin_amdgcn_global_load_lds(
        (const __attribute__((address_space(1))) void*)g,
        (__attribute__((address_space(3))) void*)l, 16, 0, 0);
}

// ---------------------------------------------------------------- embedding
__global__ void embed_kernel(const int* __restrict__ idx,
                             const float* __restrict__ tok,
                             const float* __restrict__ pos,
                             float* __restrict__ x) {
    int i = blockIdx.x * blockDim.x + threadIdx.x;   // < ROWS*D_
    int d = i % D_;
    int row = i / D_;
    int t = row % T_;
    x[i] = tok[idx[row]*D_ + d] + pos[t*D_ + d];
}

// ---------------------------------------------------------------- layernorm
// wave per row, 4 rows per 256-thread block. bf16 out.
__global__ __launch_bounds__(256)
void ln4(const float* __restrict__ x,
         const float* __restrict__ g,
         const float* __restrict__ b,
         __bf16* __restrict__ yb) {
    int w = threadIdx.x >> 6, lane = threadIdx.x & 63;
    int row = blockIdx.x * 4 + w;
    const float* xr = x + (size_t)row * D_;
    float v[6];
    #pragma unroll
    for (int i = 0; i < 6; ++i) v[i] = xr[lane + 64*i];
    float s = 0.f, sq = 0.f;
    #pragma unroll
    for (int i = 0; i < 6; ++i) { s += v[i]; sq += v[i]*v[i]; }
    for (int off = 32; off; off >>= 1) {
        s  += __shfl_xor(s,  off);
        sq += __shfl_xor(sq, off);
    }
    float mean = s * (1.0f/D_);
    float var  = sq * (1.0f/D_) - mean*mean;
    float rstd = rsqrtf(var + EPS_);
    __bf16* yr = yb + (size_t)row * D_;
    #pragma unroll
    for (int i = 0; i < 6; ++i) {
        int c = lane + 64*i;
        yr[c] = (__bf16)((v[i]-mean)*rstd*g[c] + b[c]);
    }
}

// ---------------------------------------------------------------- transpose+cast
__global__ __launch_bounds__(256)
void transpose_cast(const float* __restrict__ src, __bf16* __restrict__ dst,
                    int R, int C, int zdiv, long sA, long sB, long dbase)
{
    __shared__ float tile[32][33];
    int z = blockIdx.z;
    const float* s = src + (long)z * R * C;
    __bf16* d = dst + dbase + (long)(z / zdiv) * sA + (long)(z % zdiv) * sB;
    int c0 = blockIdx.x * 32, r0 = blockIdx.y * 32;
    int t = threadIdx.x;
    int tr = t >> 3, tc = (t & 7) * 4;
    float4 v = *(const float4*)(s + (long)(r0 + tr) * C + c0 + tc);
    tile[tr][tc+0] = v.x; tile[tr][tc+1] = v.y;
    tile[tr][tc+2] = v.z; tile[tr][tc+3] = v.w;
    __syncthreads();
    #pragma unroll
    for (int j = 0; j < 4; ++j)
        d[(long)(c0 + tr) * R + r0 + tc + j] = (__bf16)tile[tc+j][tr];
}

// head weight: Whead [384][65] fp32 -> headT [128][384] bf16 (zero-padded rows 65..127)
__global__ __launch_bounds__(256)
void head_prep(const float* __restrict__ Whead, __bf16* __restrict__ headT) {
    int i = blockIdx.x * 256 + threadIdx.x;   // < 128*384
    int n = i / D_, k = i % D_;
    headT[i] = (n < V_) ? (__bf16)Whead[k*V_ + n] : (__bf16)0.0f;
}

// ---------------------------------------------------------------- bf16 MFMA GEMM
// double-buffered LDS, XOR chunk swizzle, TM x 128 tile, BK=32, 256 thr = 4 waves.
// C[M,N] = act(A[M,K] @ Bt^T + bias) (+res);  Bt is [N][K] bf16.
// TM=128: wave 64x64 (4x4 mfma).  TM=64: wave 32x64 (2x4 mfma), grid 2x denser.
template<int TM>
__global__ __launch_bounds__(256)
void gemm_t(const __bf16* __restrict__ A, const __bf16* __restrict__ Bt,
            const float* __restrict__ bias, const float* res,
            float* outF, __bf16* outB,
            int K, int ldc, int ncols, int relu)
{
    constexpr int MI = TM / 32;              // mfma row-tiles per wave
    __shared__ __align__(16) __bf16 As[2][TM*32];
    __shared__ __align__(16) __bf16 Bs[2][128*32];
    int t = threadIdx.x;
    int w = t >> 6, lane = t & 63;
    int ln = lane & 15, quad = lane >> 4;
    int n0 = blockIdx.x * 128, m0 = blockIdx.y * TM;
    int wm = (w >> 1) * (TM/2), wn = (w & 1) * 64;

    f32x4 acc[MI][4] = {};

    const char* Ab = (const char*)A + (size_t)m0 * K * 2;
    const char* Bb = (const char*)Bt + (size_t)n0 * K * 2;
    int f0 = w*64 + lane, f1 = f0 + 256;
    int r0 = f0 >> 2, r1 = f1 >> 2;
    // swizzled source chunk within the row's 64B (keeps coalescing, breaks LDS phase)
    size_t ga0 = (size_t)r0 * K * 2 + (size_t)(((f0 & 3) ^ (r0 & 3)) * 16);
    size_t ga1 = (size_t)r1 * K * 2 + (size_t)(((f1 & 3) ^ (r1 & 3)) * 16);
    int lo0 = w*64*16, lo1 = (w*64 + 256)*16;

    int nIt = K >> 5;
    // prologue: stage k=0 into buffer 0
    glds16(Ab + ga0, (char*)As[0] + lo0);
    if constexpr (TM == 128) glds16(Ab + ga1, (char*)As[0] + lo1);
    glds16(Bb + ga0, (char*)Bs[0] + lo0);
    glds16(Bb + ga1, (char*)Bs[0] + lo1);

    for (int it = 0; it < nIt; ++it) {
        int p = it & 1;
        __syncthreads();               // drains staging of buf p
        if (it + 1 < nIt) {            // prefetch k+1 into buf p^1 (in flight during MFMA)
            size_t kb = (size_t)(it + 1) * 64;
            glds16(Ab + ga0 + kb, (char*)As[p^1] + lo0);
            if constexpr (TM == 128) glds16(Ab + ga1 + kb, (char*)As[p^1] + lo1);
            glds16(Bb + ga0 + kb, (char*)Bs[p^1] + lo0);
            glds16(Bb + ga1 + kb, (char*)Bs[p^1] + lo1);
        }
        bf16x8 af[MI], bfr[4];
        #pragma unroll
        for (int i = 0; i < MI; ++i) {
            int row = wm + i*16 + ln;
            af[i] = __builtin_bit_cast(bf16x8,
                *(const uint4*)&As[p][row*32 + ((quad ^ (row & 3)) * 8)]);
        }
        #pragma unroll
        for (int j = 0; j < 4; ++j) {
            int row = wn + j*16 + ln;
            bfr[j] = __builtin_bit_cast(bf16x8,
                *(const uint4*)&Bs[p][row*32 + ((quad ^ (row & 3)) * 8)]);
        }
        #pragma unroll
        for (int i = 0; i < MI; ++i)
            #pragma unroll
            for (int j = 0; j < 4; ++j)
                acc[i][j] = __builtin_amdgcn_mfma_f32_16x16x32_bf16(
                                af[i], bfr[j], acc[i][j], 0, 0, 0);
        __syncthreads();
    }
    #pragma unroll
    for (int i = 0; i < MI; ++i) {
        #pragma unroll
        for (int r = 0; r < 4; ++r) {
            int row = m0 + wm + i*16 + quad*4 + r;
            #pragma unroll
            for (int j = 0; j < 4; ++j) {
                int col = n0 + wn + j*16 + ln;
                if (col < ncols) {
                    float v = acc[i][j][r];
                    if (bias) v += bias[col];
                    if (relu) v = fmaxf(v, 0.f);
                    if (res)  v += res[(size_t)row*ldc + col];
                    if (outF) outF[(size_t)row*ldc + col] = v;
                    if (outB) outB[(size_t)row*ldc + col] = (__bf16)v;
                }
            }
        }
    }
}

// ---------------------------------------------------------------- MFMA flash attention
// one block per (b,h); 32-row q-tiles; wave w owns q-tiles {w, 7-w} (9 s-subtiles each).
// K [256][72] LDS; V^T bank-swizzled [64 e][264 s]; per-wave P [32][40]. ~81KB -> 2 blocks/CU.
__global__ __launch_bounds__(256, 2)
void attn4(const __bf16* __restrict__ qkv, __bf16* __restrict__ o)
{
    __shared__ __align__(16) __bf16 Ks[256*72];
    __shared__ __align__(16) __bf16 Vt[64*264];
    __shared__ __align__(16) __bf16 Pw[4][32*40];
    int bid = blockIdx.x;
    int h = bid % H_;
    int b = bid / H_;
    int t = threadIdx.x;
    int w = t >> 6, lane = t & 63;
    int ln = lane & 15, quad = lane >> 4;
    const size_t rowb = (size_t)b * T_ * QKVN;
    const int hoff = h * HS_;
    const float scale = 0.05103103630798288f;   // 1/sqrt(384)

    // stage K rows + swizzled V^T: elem (e, s) at Vt[e*264 + ((s>>3)^((e>>3)&3))*8 + (s&7)]
    for (int c = t; c < 2048; c += 256) {
        int r = c >> 3, e0 = (c & 7) * 8;
        uint4 uk = *(const uint4*)(qkv + rowb + (size_t)r*QKVN + 384 + hoff + e0);
        *(uint4*)&Ks[r*72 + e0] = uk;
        uint4 uv = *(const uint4*)(qkv + rowb + (size_t)r*QKVN + 768 + hoff + e0);
        bf16x8 v8 = u4_to_bf8(uv);
        #pragma unroll
        for (int j = 0; j < 8; ++j) {
            int e = e0 + j;
            Vt[e*264 + (((r >> 3) ^ ((e >> 3) & 3)) * 8) + (r & 7)] = v8[j];
        }
    }

    // Q fragments for both q-tiles (A-layout: m=ln, k=quad*8+j)
    int qis[2] = { w, 7 - w };
    uint4 Qf[2][2][2];
    #pragma unroll
    for (int tl = 0; tl < 2; ++tl)
        #pragma unroll
        for (int mi = 0; mi < 2; ++mi)
            #pragma unroll
            for (int kc = 0; kc < 2; ++kc)
                Qf[tl][mi][kc] = *(const uint4*)(qkv + rowb +
                    (size_t)(qis[tl]*32 + mi*16 + ln)*QKVN + hoff + kc*32 + quad*8);

    __syncthreads();

    __bf16* P = Pw[w];
    #pragma unroll
    for (int tl = 0; tl < 2; ++tl) {
        int qi = qis[tl];
        f32x4 O[2][4] = {};
        float mst[2][4], lst[2][4];
        #pragma unroll
        for (int mi = 0; mi < 2; ++mi)
            #pragma unroll
            for (int r = 0; r < 4; ++r) { mst[mi][r] = -INFINITY; lst[mi][r] = 0.f; }

        for (int st = 0; st <= qi; ++st) {
            int sb = st * 32;
            f32x4 S[2][2] = {};
            #pragma unroll
            for (int kc = 0; kc < 2; ++kc) {
                uint4 Kf[2];
                #pragma unroll
                for (int ji = 0; ji < 2; ++ji)
                    Kf[ji] = *(const uint4*)&Ks[(sb + ji*16 + ln)*72 + kc*32 + quad*8];
                #pragma unroll
                for (int mi = 0; mi < 2; ++mi) {
                    bf16x8 qa = __builtin_bit_cast(bf16x8, Qf[tl][mi][kc]);
                    #pragma unroll
                    for (int ji = 0; ji < 2; ++ji)
                        S[mi][ji] = __builtin_amdgcn_mfma_f32_16x16x32_bf16(
                            qa, __builtin_bit_cast(bf16x8, Kf[ji]), S[mi][ji], 0, 0, 0);
                }
            }
            int diag = (st == qi);
            #pragma unroll
            for (int mi = 0; mi < 2; ++mi)
                #pragma unroll
                for (int ji = 0; ji < 2; ++ji)
                    #pragma unroll
                    for (int r = 0; r < 4; ++r) {
                        float v = S[mi][ji][r] * scale;
                        if (diag && (ji*16 + ln) > (mi*16 + quad*4 + r)) v = -INFINITY;
                        S[mi][ji][r] = v;
                    }
            // online softmax per row (cols spread over 16-lane group)
            #pragma unroll
            for (int mi = 0; mi < 2; ++mi)
                #pragma unroll
                for (int r = 0; r < 4; ++r) {
                    float mx = fmaxf(S[mi][0][r], S[mi][1][r]);
                    #pragma unroll
                    for (int off = 1; off < 16; off <<= 1)
                        mx = fmaxf(mx, __shfl_xor(mx, off));
                    float mn = fmaxf(mst[mi][r], mx);
                    float al = __expf(mst[mi][r] - mn);
                    mst[mi][r] = mn;
                    float p0 = __expf(S[mi][0][r] - mn);
                    float p1 = __expf(S[mi][1][r] - mn);
                    S[mi][0][r] = p0; S[mi][1][r] = p1;
                    float rs = p0 + p1;
                    #pragma unroll
                    for (int off = 1; off < 16; off <<= 1)
                        rs += __shfl_xor(rs, off);
                    lst[mi][r] = lst[mi][r]*al + rs;
                    #pragma unroll
                    for (int ei = 0; ei < 4; ++ei) O[mi][ei][r] *= al;
                }
            // P (C layout) -> per-wave LDS -> A layout
            #pragma unroll
            for (int mi = 0; mi < 2; ++mi)
                #pragma unroll
                for (int ji = 0; ji < 2; ++ji)
                    #pragma unroll
                    for (int r = 0; r < 4; ++r)
                        P[(mi*16 + quad*4 + r)*40 + ji*16 + ln] = (__bf16)S[mi][ji][r];
            uint4 Pf[2], Vf[4];
            #pragma unroll
            for (int mi = 0; mi < 2; ++mi)
                Pf[mi] = *(const uint4*)&P[(mi*16 + ln)*40 + quad*8];
            #pragma unroll
            for (int ei = 0; ei < 4; ++ei) {
                int e = ei*16 + ln;
                Vf[ei] = *(const uint4*)&Vt[e*264 + (((st*4 + quad) ^ ((e >> 3) & 3)) * 8)];
            }
            #pragma unroll
            for (int mi = 0; mi < 2; ++mi)
                #pragma unroll
                for (int ei = 0; ei < 4; ++ei)
                    O[mi][ei] = __builtin_amdgcn_mfma_f32_16x16x32_bf16(
                        __builtin_bit_cast(bf16x8, Pf[mi]),
                        __builtin_bit_cast(bf16x8, Vf[ei]), O[mi][ei], 0, 0, 0);
        }
        // epilogue for this q-tile
        #pragma unroll
        for (int mi = 0; mi < 2; ++mi)
            #pragma unroll
            for (int r = 0; r < 4; ++r) {
                float inv = 1.0f / lst[mi][r];
                size_t row = (size_t)(b*T_ + qi*32 + mi*16 + quad*4 + r);
                #pragma unroll
                for (int ei = 0; ei < 4; ++ei)
                    o[row*D_ + hoff + ei*16 + ln] = (__bf16)(O[mi][ei][r] * inv);
            }
    }
}

// ---------------------------------------------------------------- loss
__global__ __launch_bounds__(256)
void loss2(const float* __restrict__ logits,
           const int* __restrict__ tg,
           float* __restrict__ loss)
{
    int row = blockIdx.x * 256 + threadIdx.x;
    const float* lr = logits + (size_t)row * V_;
    float m = -INFINITY;
    for (int c = 0; c < V_; ++c) m = fmaxf(m, lr[c]);
    float s = 0.f;
    for (int c = 0; c < V_; ++c) s += __expf(lr[c] - m);
    float val = -(lr[tg[row]] - m - __logf(s)) * (1.0f/ROWS);
    for (int off = 32; off; off >>= 1) val += __shfl_xor(val, off);
    __shared__ float red[4];
    int w = threadIdx.x >> 6, lane = threadIdx.x & 63;
    if (lane == 0) red[w] = val;
    __syncthreads();
    if (threadIdx.x == 0)
        atomicAdd(loss, red[0]+red[1]+red[2]+red[3]);
}

// ---------------------------------------------------------------- launch
extern "C" void kernel_launch(void* const* d_in, const int* in_sizes, int n_in,
                              void* d_out, int out_size, void* d_ws, size_t ws_size,
                              hipStream_t stream)
{
    const int*   idx     = (const int*)  d_in[0];
    const int*   targets = (const int*)  d_in[1];
    const float* tok     = (const float*)d_in[2];
    const float* pos     = (const float*)d_in[3];
    const float* Wq      = (const float*)d_in[4];
    const float* Wk      = (const float*)d_in[5];
    const float* Wv      = (const float*)d_in[6];
    const float* Wproj   = (const float*)d_in[7];
    const float* bproj   = (const float*)d_in[8];
    const float* W1      = (const float*)d_in[9];
    const float* b1      = (const float*)d_in[10];
    const float* W2      = (const float*)d_in[11];
    const float* b2      = (const float*)d_in[12];
    const float* ln1g    = (const float*)d_in[13];
    const float* ln1b    = (const float*)d_in[14];
    const float* lnfg    = (const float*)d_in[15];
    const float* lnfb    = (const float*)d_in[16];
    const float* Whead   = (const float*)d_in[17];
    const float* bhead   = (const float*)d_in[18];

    float* logits = (float*)d_out;
    float* loss   = logits + (size_t)ROWS * V_;

    const size_t SZ = (size_t)ROWS * D_;             // 6291456
    const size_t RGELEMS = (size_t)ROWS * 4 * D_;    // 25165824 bf16 elems

    float*  x   = (float*)d_ws;                      // SZ f32
    __bf16* yb  = (__bf16*)(x + SZ);                 // SZ bf16
    __bf16* Rg  = yb + SZ;                           // RGELEMS bf16 (qkv / hid)
    __bf16* qkv = Rg;                                // ROWS*1152
    __bf16* hid = Rg;                                // ROWS*1536
    __bf16* o   = Rg + RGELEMS;                      // SZ bf16
    __bf16* qkvT  = o + SZ;                          // L*1152*384
    __bf16* projT = qkvT + (size_t)L_*QKVN*D_;       // L*384*384
    __bf16* w1T   = projT + (size_t)L_*D_*D_;        // L*1536*384
    __bf16* w2T   = w1T + (size_t)L_*D_*4*D_;        // L*384*1536
    __bf16* headT = w2T + (size_t)L_*D_*4*D_;        // 128*384

    // weight conversion (transpose to [N][K] bf16)
    transpose_cast<<<dim3(2,12,36),256,0,stream>>>(Wq, qkvT, D_, HS_, H_,
        (long)QKVN*D_, (long)HS_*D_, 0L);
    transpose_cast<<<dim3(2,12,36),256,0,stream>>>(Wk, qkvT, D_, HS_, H_,
        (long)QKVN*D_, (long)HS_*D_, (long)D_*D_);
    transpose_cast<<<dim3(2,12,36),256,0,stream>>>(Wv, qkvT, D_, HS_, H_,
        (long)QKVN*D_, (long)HS_*D_, 2L*D_*D_);
    transpose_cast<<<dim3(12,12,6),256,0,stream>>>(Wproj, projT, D_, D_, 1,
        (long)D_*D_, 0L, 0L);
    transpose_cast<<<dim3(48,12,6),256,0,stream>>>(W1, w1T, D_, 4*D_, 1,
        (long)D_*4*D_, 0L, 0L);
    transpose_cast<<<dim3(12,48,6),256,0,stream>>>(W2, w2T, 4*D_, D_, 1,
        (long)D_*4*D_, 0L, 0L);
    head_prep<<<(128*D_)/256, 256, 0, stream>>>(Whead, headT);

    embed_kernel<<<(ROWS*D_)/256, 256, 0, stream>>>(idx, tok, pos, x);

    for (int l = 0; l < L_; ++l) {
        ln4<<<ROWS/4, 256, 0, stream>>>(x, ln1g + l*D_, ln1b + l*D_, yb);
        gemm_t<128><<<dim3(QKVN/128, ROWS/128), 256, 0, stream>>>(
            yb, qkvT + (size_t)l*QKVN*D_, nullptr, nullptr, nullptr, qkv,
            D_, QKVN, QKVN, 0);
        attn4<<<B_*H_, 256, 0, stream>>>(qkv, o);
        gemm_t<64><<<dim3(D_/128, ROWS/64), 256, 0, stream>>>(
            o, projT + (size_t)l*D_*D_, bproj + l*D_, x, x, nullptr,
            D_, D_, D_, 0);
        ln4<<<ROWS/4, 256, 0, stream>>>(x, ln1g + l*D_, ln1b + l*D_, yb);
        gemm_t<128><<<dim3(4*D_/128, ROWS/128), 256, 0, stream>>>(
            yb, w1T + (size_t)l*D_*4*D_, b1 + l*4*D_, nullptr, nullptr, hid,
            D_, 4*D_, 4*D_, 1);
        gemm_t<64><<<dim3(D_/128, ROWS/64), 256, 0, stream>>>(
            hid, w2T + (size_t)l*D_*4*D_, b2 + l*D_, x, x, nullptr,
            4*D_, D_, D_, 0);
    }
    ln4<<<ROWS/4, 256, 0, stream>>>(x, lnfg, lnfb, yb);
    gemm_t<64><<<dim3(1, ROWS/64), 256, 0, stream>>>(
        yb, headT, bhead, nullptr, logits, nullptr,
        D_, V_, V_, 0);
    hipMemsetAsync(loss, 0, sizeof(float), stream);
    loss2<<<ROWS/256, 256, 0, stream>>>(logits, targets, loss);
}